// Round 1
// baseline (2455.563 us; speedup 1.0000x reference)
//
#include <hip/hip_runtime.h>
#include <math.h>

// B=2, T=1024, D=1024, H=8, Dh=128, L=11, conv=4
#define T_SEQ 1024
#define SCALE_Q 0.08838834764831845f

static __device__ __forceinline__ float sigm(float x){ return 1.f/(1.f+__expf(-x)); }

// ---------------- generic tiled f32 GEMM: C[M,N] = A[M,K] @ B[K,N] ----------------
__global__ __launch_bounds__(256) void gemm_f32(const float* __restrict__ A,
    const float* __restrict__ B, float* __restrict__ C, int M, int N, int K)
{
  __shared__ float As[16][64];
  __shared__ float Bs[16][64];
  int tid = threadIdx.x;
  int bm = blockIdx.y * 64, bn = blockIdx.x * 64;
  int tx = tid & 15, ty = tid >> 4;
  int am = tid >> 2, ak = (tid & 3) << 2;
  int bk = tid >> 4, bn4 = (tid & 15) << 2;
  float acc[4][4] = {};
  for (int k0 = 0; k0 < K; k0 += 16) {
    float4 a4 = *(const float4*)&A[(size_t)(bm+am)*K + k0 + ak];
    As[ak+0][am] = a4.x; As[ak+1][am] = a4.y; As[ak+2][am] = a4.z; As[ak+3][am] = a4.w;
    float4 b4;
    int col = bn + bn4;
    if (col + 3 < N) {
      b4 = *(const float4*)&B[(size_t)(k0+bk)*N + col];
    } else {
      const float* bp = &B[(size_t)(k0+bk)*N];
      b4.x = (col+0<N)? bp[col+0]:0.f; b4.y = (col+1<N)? bp[col+1]:0.f;
      b4.z = (col+2<N)? bp[col+2]:0.f; b4.w = (col+3<N)? bp[col+3]:0.f;
    }
    *(float4*)&Bs[bk][bn4] = b4;
    __syncthreads();
    #pragma unroll
    for (int kk = 0; kk < 16; ++kk) {
      float4 av = *(const float4*)&As[kk][ty<<2];
      float4 bv = *(const float4*)&Bs[kk][tx<<2];
      float a_[4] = {av.x,av.y,av.z,av.w};
      float b_[4] = {bv.x,bv.y,bv.z,bv.w};
      #pragma unroll
      for (int i2 = 0; i2 < 4; ++i2)
        #pragma unroll
        for (int j2 = 0; j2 < 4; ++j2)
          acc[i2][j2] += a_[i2]*b_[j2];
    }
    __syncthreads();
  }
  #pragma unroll
  for (int i2 = 0; i2 < 4; ++i2) {
    int row = bm + (ty<<2) + i2;
    #pragma unroll
    for (int j2 = 0; j2 < 4; ++j2) {
      int col = bn + (tx<<2) + j2;
      if (col < N) C[(size_t)row*N + col] = acc[i2][j2];
    }
  }
}

// -------- depthwise causal conv(4) + silu, optional per-head l2norm --------
// one block per (b,t); 256 threads x 4 channels. mode 0: q (l2norm*SCALE),
// mode 1: k (l2norm), mode 2: v (none)
__global__ __launch_bounds__(256) void conv_silu(const float* __restrict__ X,
    const float* __restrict__ W, float* __restrict__ Y, int mode)
{
  int row = blockIdx.x;
  int b = row >> 10, t = row & 1023;
  int tid = threadIdx.x;
  int c0 = tid << 2;
  float w[4][4];
  #pragma unroll
  for (int c = 0; c < 4; ++c) {
    float4 wv = *(const float4*)&W[(c0 + c)*4];
    w[c][0]=wv.x; w[c][1]=wv.y; w[c][2]=wv.z; w[c][3]=wv.w;
  }
  float acc[4] = {0.f,0.f,0.f,0.f};
  #pragma unroll
  for (int j = 0; j < 4; ++j) {
    int tt = t - 3 + j;
    if (tt >= 0) {
      float4 xv = *(const float4*)&X[(size_t)(b*1024 + tt)*1024 + c0];
      acc[0] += w[0][j]*xv.x; acc[1] += w[1][j]*xv.y;
      acc[2] += w[2][j]*xv.z; acc[3] += w[3][j]*xv.w;
    }
  }
  #pragma unroll
  for (int c = 0; c < 4; ++c) acc[c] *= sigm(acc[c]);  // silu
  if (mode < 2) {
    float ss = acc[0]*acc[0]+acc[1]*acc[1]+acc[2]*acc[2]+acc[3]*acc[3];
    ss += __shfl_xor(ss, 1); ss += __shfl_xor(ss, 2); ss += __shfl_xor(ss, 4);
    ss += __shfl_xor(ss, 8); ss += __shfl_xor(ss, 16);   // 32 lanes = one 128-d head
    float r = rsqrtf(ss + 1e-6f);
    if (mode == 0) r *= SCALE_Q;
    acc[0]*=r; acc[1]*=r; acc[2]*=r; acc[3]*=r;
  }
  float4 yv; yv.x=acc[0]; yv.y=acc[1]; yv.z=acc[2]; yv.w=acc[3];
  *(float4*)&Y[(size_t)(b*1024 + t)*1024 + c0] = yv;
}

// -------- per-(b,h) log-decay cumsum: gc[bh][t] --------
__global__ __launch_bounds__(256) void gc_kernel(const float* __restrict__ xa,
    const float* __restrict__ A_log, const float* __restrict__ dt_bias,
    float* __restrict__ gc)
{
  __shared__ float part[16][17];
  int tid = threadIdx.x;
  int bh = tid >> 4, seg = tid & 15;
  int b = bh >> 3, h = bh & 7;
  float aexp = __expf(A_log[h]);
  float db = dt_bias[h];
  int t0 = seg * 64;
  float s = 0.f;
  for (int t = t0; t < t0+64; ++t) {
    float z = xa[(size_t)(b*1024+t)*8 + h] + db;
    float sp = (z > 20.f) ? z : log1pf(__expf(z));
    s += -aexp * sp;
  }
  part[bh][seg] = s;
  __syncthreads();
  float run = 0.f;
  for (int j = 0; j < seg; ++j) run += part[bh][j];
  for (int t = t0; t < t0+64; ++t) {
    float z = xa[(size_t)(b*1024+t)*8 + h] + db;
    float sp = (z > 20.f) ? z : log1pf(__expf(z));
    run += -aexp * sp;
    gc[bh*1024 + t] = run;
  }
}

// -------- chunked gated-delta-rule solve for u  --------
// grid: 32 blocks = (b,h) x dv-half(64). chunk C=32, running state S[128][64].
__global__ __launch_bounds__(256) void usolve(const float* __restrict__ Kg,
    const float* __restrict__ Vg, const float* __restrict__ xb,
    const float* __restrict__ gcg, float* __restrict__ Ug)
{
  int blk = blockIdx.x;
  int bh = blk >> 1, half = blk & 1;
  int b = bh >> 3, h = bh & 7;
  int d0g = half * 64;
  __shared__ float S[128][65];
  __shared__ float Kc[32][129];
  __shared__ float Uc[32][65];
  __shared__ float Ac[32][33];
  __shared__ float gcl[33];
  __shared__ float bl[32];
  __shared__ float ed[32];
  int tid = threadIdx.x;
  for (int e = tid; e < 128*64; e += 256) S[e>>6][e&63] = 0.f;
  const float* gcb = gcg + bh*1024;
  for (int i = 0; i < 32; ++i) {
    int a = i << 5;
    for (int e = tid; e < 32*128; e += 256) {
      int t = e >> 7, kk = e & 127;
      Kc[t][kk] = Kg[(size_t)(b*1024 + a + t)*1024 + h*128 + kk];
    }
    if (tid < 32) {
      gcl[tid] = gcb[a + tid];
      bl[tid] = sigm(xb[(size_t)(b*1024 + a + tid)*8 + h]);
    }
    if (tid == 32) gcl[32] = (i < 31) ? gcb[a+32] : 0.f;
    __syncthreads();
    // Phase A: strict in-chunk Akk with beta folded: Ac[t][s] = b_t (k_t.k_s) e^{gc_t-gc_s}
    {
      int t = tid >> 3, s0 = (tid & 7) << 2;
      float dot[4] = {0.f,0.f,0.f,0.f};
      for (int kk = 0; kk < 128; ++kk) {
        float kt = Kc[t][kk];
        dot[0] += kt * Kc[s0+0][kk];
        dot[1] += kt * Kc[s0+1][kk];
        dot[2] += kt * Kc[s0+2][kk];
        dot[3] += kt * Kc[s0+3][kk];
      }
      #pragma unroll
      for (int c = 0; c < 4; ++c) {
        int s = s0 + c;
        Ac[t][s] = (s < t) ? bl[t]*dot[c]*__expf(gcl[t]-gcl[s]) : 0.f;
      }
    }
    // Phase B: rhs = beta*v - beta*e^{gc_t-gc_a} * (K S)
    {
      int t = tid >> 3, dq = (tid & 7) << 3;
      float acc[8] = {};
      for (int kk = 0; kk < 128; ++kk) {
        float kt = Kc[t][kk];
        #pragma unroll
        for (int c = 0; c < 8; ++c) acc[c] += kt * S[kk][dq+c];
      }
      float gam = __expf(gcl[t] - gcl[0]);
      float bt = bl[t];
      #pragma unroll
      for (int c = 0; c < 8; ++c) {
        float vv = Vg[(size_t)(b*1024 + a + t)*1024 + h*128 + d0g + dq + c];
        Uc[t][dq+c] = bt*vv - bt*gam*acc[c];
      }
    }
    __syncthreads();
    // Phase C: in-chunk forward substitution (one wave, lane = dv column, lockstep)
    if (tid < 64) {
      int d = tid;
      for (int t = 1; t < 32; ++t) {
        float acc = 0.f;
        for (int s = 0; s < t; ++s) acc += Ac[t][s]*Uc[s][d];
        Uc[t][d] -= acc;
      }
    }
    __syncthreads();
    if (tid < 32) ed[tid] = (i < 31) ? __expf(gcl[32] - gcl[tid]) : 0.f;
    __syncthreads();
    // write u
    {
      int t = tid >> 3, dq = (tid & 7) << 3;
      #pragma unroll
      for (int c = 0; c < 8; ++c)
        Ug[(size_t)(b*1024 + a + t)*1024 + h*128 + d0g + dq + c] = Uc[t][dq+c];
    }
    // Phase D: S <- decay*S + K^T (e^{gc_next - gc_t} u)
    if (i < 31) {
      float dec = __expf(gcl[32] - gcl[0]);
      int kk = tid >> 1, dq = (tid & 1) << 5;
      float sacc[32];
      #pragma unroll
      for (int c = 0; c < 32; ++c) sacc[c] = dec * S[kk][dq+c];
      for (int t = 0; t < 32; ++t) {
        float wv = ed[t]*Kc[t][kk];
        #pragma unroll
        for (int c = 0; c < 32; ++c) sacc[c] += wv * Uc[t][dq+c];
      }
      #pragma unroll
      for (int c = 0; c < 32; ++c) S[kk][dq+c] = sacc[c];
    }
    __syncthreads();
  }
}

// -------- log-linear readout: o = ((q k^T) * exp(dgc) * lam[level]) @ u --------
// grid: 512 = (b,h) x 32 t-chunks of 32
__global__ __launch_bounds__(256) void readout(const float* __restrict__ Qg,
    const float* __restrict__ Kg, const float* __restrict__ Ug,
    const float* __restrict__ gcg, const float* __restrict__ xl,
    float* __restrict__ Og)
{
  int blk = blockIdx.x;
  int bh = blk >> 5, ic = blk & 31;
  int b = bh >> 3, h = bh & 7;
  int a = ic << 5;
  __shared__ float Qc[32][129];
  __shared__ float KU[32][129];
  __shared__ float P[32][33];
  __shared__ float lamS[32][11];
  __shared__ float gct[32], gcs[32];
  int tid = threadIdx.x;
  for (int e = tid; e < 32*128; e += 256) {
    int t = e >> 7, kk = e & 127;
    Qc[t][kk] = Qg[(size_t)(b*1024 + a + t)*1024 + h*128 + kk];
  }
  if (tid < 32) gct[tid] = gcg[bh*1024 + a + tid];
  for (int e = tid; e < 32*11; e += 256) {
    int t = e / 11, l = e % 11;
    lamS[t][l] = sigm(xl[(size_t)(b*1024 + a + t)*88 + h*11 + l]);
  }
  float acc[16] = {};
  int rt = tid >> 3;              // shared row index (t) for both phases
  int ps0 = (tid & 7) << 2;       // P phase: 4 s-columns
  int udq = (tid & 7) << 4;       // update phase: 16 d-columns
  for (int j = 0; j <= ic; ++j) {
    int s0 = j << 5;
    __syncthreads();              // protect KU before overwrite
    for (int e = tid; e < 32*128; e += 256) {
      int s = e >> 7, kk = e & 127;
      KU[s][kk] = Kg[(size_t)(b*1024 + s0 + s)*1024 + h*128 + kk];
    }
    if (tid < 32) gcs[tid] = gcg[bh*1024 + s0 + tid];
    __syncthreads();
    // P[t][s] = (q_t.k_s) e^{gc_t-gc_s} lam_t[level] (causal)
    {
      float dot[4] = {0.f,0.f,0.f,0.f};
      for (int kk = 0; kk < 128; ++kk) {
        float qv = Qc[rt][kk];
        dot[0] += qv * KU[ps0+0][kk];
        dot[1] += qv * KU[ps0+1][kk];
        dot[2] += qv * KU[ps0+2][kk];
        dot[3] += qv * KU[ps0+3][kk];
      }
      int tg = a + rt;
      #pragma unroll
      for (int c = 0; c < 4; ++c) {
        int sg = s0 + ps0 + c;
        float pv = 0.f;
        if (sg <= tg) {
          int lev = 31 - __clz((unsigned)((tg+1) ^ sg));
          lev = lev > 10 ? 10 : lev;
          pv = dot[c] * __expf(gct[rt] - gcs[ps0+c]) * lamS[rt][lev];
        }
        P[rt][ps0+c] = pv;
      }
    }
    __syncthreads();
    // reuse KU for the u tile
    for (int e = tid; e < 32*128; e += 256) {
      int s = e >> 7, kk = e & 127;
      KU[s][kk] = Ug[(size_t)(b*1024 + s0 + s)*1024 + h*128 + kk];
    }
    __syncthreads();
    for (int s = 0; s < 32; ++s) {
      float p = P[rt][s];
      #pragma unroll
      for (int c = 0; c < 16; ++c) acc[c] += p * KU[s][udq + c];
    }
  }
  #pragma unroll
  for (int c = 0; c < 16; ++c)
    Og[(size_t)(b*1024 + a + rt)*1024 + h*128 + udq + c] = acc[c];
}

// -------- gated RMSNorm: y = o * rsqrt(mean(o^2)+eps) * norm_w * silu(gate) --------
__global__ __launch_bounds__(64) void normgate(const float* __restrict__ O,
    const float* __restrict__ G, const float* __restrict__ norm_w,
    float* __restrict__ Y)
{
  int row = blockIdx.x;            // (b*T+t)*8 + h
  int lane = threadIdx.x;
  size_t base = (size_t)(row >> 3)*1024 + (size_t)(row & 7)*128;
  float2 o = *(const float2*)&O[base + lane*2];
  float ss = o.x*o.x + o.y*o.y;
  #pragma unroll
  for (int m = 1; m < 64; m <<= 1) ss += __shfl_xor(ss, m);
  float r = rsqrtf(ss * (1.f/128.f) + 1e-5f);
  float2 g = *(const float2*)&G[base + lane*2];
  float2 y;
  y.x = o.x * r * norm_w[lane*2+0] * (g.x * sigm(g.x));
  y.y = o.y * r * norm_w[lane*2+1] * (g.y * sigm(g.y));
  *(float2*)&Y[base + lane*2] = y;
}

extern "C" void kernel_launch(void* const* d_in, const int* in_sizes, int n_in,
                              void* d_out, int out_size, void* d_ws, size_t ws_size,
                              hipStream_t stream)
{
  const float* x    = (const float*)d_in[0];
  const float* Wq   = (const float*)d_in[3];
  const float* Wk   = (const float*)d_in[4];
  const float* Wv   = (const float*)d_in[5];
  const float* Wb   = (const float*)d_in[6];
  const float* Wa   = (const float*)d_in[7];
  const float* Wl   = (const float*)d_in[8];
  const float* Wg   = (const float*)d_in[9];
  const float* Wo   = (const float*)d_in[10];
  const float* cq   = (const float*)d_in[11];
  const float* ck   = (const float*)d_in[12];
  const float* cv   = (const float*)d_in[13];
  const float* A_log   = (const float*)d_in[14];
  const float* dt_bias = (const float*)d_in[15];
  const float* norm_w  = (const float*)d_in[16];
  float* out = (float*)d_out;
  float* ws = (float*)d_ws;
  const size_t M1 = (size_t)2048*1024;
  float* xq = ws;
  float* xk = ws + 1*M1;
  float* xv = ws + 2*M1;
  float* xg = ws + 3*M1;
  float* qb = ws + 4*M1;
  float* kb = ws + 5*M1;
  float* vb = ws + 6*M1;
  float* xb = ws + 7*M1;
  float* xa = xb + 16384;
  float* xl = xa + 16384;
  float* gc = xl + 2048*88;
  float* ub = xq;   // xq dead after conv
  float* ob = xk;   // xk dead after conv
  float* yb = xv;   // xv dead after conv

  dim3 blk(256);
  dim3 g1024(16, 32), g8(1, 32), g88(2, 32);
  gemm_f32<<<g1024, blk, 0, stream>>>(x, Wq, xq, 2048, 1024, 1024);
  gemm_f32<<<g1024, blk, 0, stream>>>(x, Wk, xk, 2048, 1024, 1024);
  gemm_f32<<<g1024, blk, 0, stream>>>(x, Wv, xv, 2048, 1024, 1024);
  gemm_f32<<<g1024, blk, 0, stream>>>(x, Wg, xg, 2048, 1024, 1024);
  gemm_f32<<<g8,    blk, 0, stream>>>(x, Wb, xb, 2048, 8, 1024);
  gemm_f32<<<g8,    blk, 0, stream>>>(x, Wa, xa, 2048, 8, 1024);
  gemm_f32<<<g88,   blk, 0, stream>>>(x, Wl, xl, 2048, 88, 1024);
  conv_silu<<<dim3(2048), blk, 0, stream>>>(xq, cq, qb, 0);
  conv_silu<<<dim3(2048), blk, 0, stream>>>(xk, ck, kb, 1);
  conv_silu<<<dim3(2048), blk, 0, stream>>>(xv, cv, vb, 2);
  gc_kernel<<<dim3(1), blk, 0, stream>>>(xa, A_log, dt_bias, gc);
  usolve<<<dim3(32), blk, 0, stream>>>(kb, vb, xb, gc, ub);
  readout<<<dim3(512), blk, 0, stream>>>(qb, kb, ub, gc, xl, ob);
  normgate<<<dim3(16384), dim3(64), 0, stream>>>(ob, xg, norm_w, yb);
  gemm_f32<<<g1024, blk, 0, stream>>>(yb, Wo, out, 2048, 1024, 1024);
}

// Round 2
// 935.089 us; speedup vs baseline: 2.6260x; 2.6260x over previous
//
#include <hip/hip_runtime.h>
#include <hip/hip_bf16.h>
#include <math.h>

// B=2, T=1024, D=1024, H=8, Dh=128, L=11, conv=4; chunk C=64, 16 chunks/bh
#define SCALE_Q 0.08838834764831845f

typedef __bf16 bf16x8 __attribute__((ext_vector_type(8)));
typedef float f32x4 __attribute__((ext_vector_type(4)));

static __device__ __forceinline__ float sigm(float x){ return 1.f/(1.f+__expf(-x)); }
static __device__ __forceinline__ ushort f2b(float v){
  __hip_bfloat16 t = __float2bfloat16(v);
  return __builtin_bit_cast(ushort, t);
}

// ---------------- cast x f32 -> bf16 ----------------
__global__ __launch_bounds__(256) void cast_x(const float* __restrict__ X,
    ushort* __restrict__ Y)
{
  int idx = blockIdx.x*256 + threadIdx.x;
  float4 v = *(const float4*)&X[(size_t)idx*4];
  ushort4 o; o.x=f2b(v.x); o.y=f2b(v.y); o.z=f2b(v.z); o.w=f2b(v.w);
  *(ushort4*)&Y[(size_t)idx*4] = o;
}

// ---------------- transpose + cast: Wt[n][k] = bf16(W[k][n]), 1024x1024 ----------------
__global__ __launch_bounds__(256) void transcast(const float* __restrict__ W,
    ushort* __restrict__ Wt)
{
  __shared__ float tile[32][36];
  int n0 = blockIdx.x*32, k0 = blockIdx.y*32;
  int tid = threadIdx.x;
  int r = tid >> 3, c4 = (tid & 7) << 2;
  *(float4*)&tile[r][c4] = *(const float4*)&W[(size_t)(k0 + r)*1024 + n0 + c4];
  __syncthreads();
  ushort4 o;
  o.x = f2b(tile[c4+0][r]); o.y = f2b(tile[c4+1][r]);
  o.z = f2b(tile[c4+2][r]); o.w = f2b(tile[c4+3][r]);
  *(ushort4*)&Wt[(size_t)(n0 + r)*1024 + k0 + c4] = o;
}

// ---------------- concat small weights: Wsm[k][0:8]=Wb, [8:16]=Wa, [16:104]=Wl ----------------
__global__ __launch_bounds__(256) void copy_wsmall(const float* __restrict__ Wb,
    const float* __restrict__ Wa, const float* __restrict__ Wl, float* __restrict__ Wsm)
{
  int idx = blockIdx.x*256 + threadIdx.x;
  if (idx >= 1024*104) return;
  int k = idx / 104, c = idx % 104;
  float v = (c < 8) ? Wb[k*8+c] : (c < 16) ? Wa[k*8+(c-8)] : Wl[k*88+(c-16)];
  Wsm[idx] = v;
}

// ---------------- bf16 MFMA GEMM: C[M,N] = A[M,K] @ Bt[N,K]^T, C f32, split cols ----------------
// 128x128 tile, BK=32, 4 waves (2x2 quadrants of 64x64), 16x16x32 MFMA
__global__ __launch_bounds__(256) void gemm_bf16(const ushort* __restrict__ A,
    const ushort* __restrict__ Bt, float* __restrict__ C0, float* __restrict__ C1,
    int M, int N, int K, int nsplit, int ld0, int ld1)
{
  __shared__ ushort As[128*32];
  __shared__ ushort Bs[128*32];
  int tid = threadIdx.x;
  int bm = blockIdx.y * 128, bn = blockIdx.x * 128;
  int wave = tid >> 6, lane = tid & 63;
  int wm = (wave >> 1) * 64, wn = (wave & 1) * 64;
  int l16 = lane & 15, kh = lane >> 4;
  f32x4 acc[4][4] = {};
  int rowA0 = tid >> 2, boA = (tid & 3) * 16;   // 64B per LDS row (32 bf16)
  for (int k0 = 0; k0 < K; k0 += 32) {
    #pragma unroll
    for (int j = 0; j < 2; ++j) {
      int row = rowA0 + j*64;
      const char* gA = (const char*)A + (((size_t)(bm+row)*K + k0)*2 + boA);
      const char* gB = (const char*)Bt + (((size_t)(bn+row)*K + k0)*2 + boA);
      __builtin_amdgcn_global_load_lds((const __attribute__((address_space(1))) unsigned*)gA,
        (__attribute__((address_space(3))) unsigned*)((char*)As + row*64 + boA), 16, 0, 0);
      __builtin_amdgcn_global_load_lds((const __attribute__((address_space(1))) unsigned*)gB,
        (__attribute__((address_space(3))) unsigned*)((char*)Bs + row*64 + boA), 16, 0, 0);
    }
    __syncthreads();
    bf16x8 af[4], bfr[4];
    #pragma unroll
    for (int i = 0; i < 4; ++i)
      af[i] = *(bf16x8*)((char*)As + (wm + i*16 + l16)*64 + kh*16);
    #pragma unroll
    for (int j = 0; j < 4; ++j)
      bfr[j] = *(bf16x8*)((char*)Bs + (wn + j*16 + l16)*64 + kh*16);
    #pragma unroll
    for (int i = 0; i < 4; ++i)
      #pragma unroll
      for (int j = 0; j < 4; ++j)
        acc[i][j] = __builtin_amdgcn_mfma_f32_16x16x32_bf16(af[i], bfr[j], acc[i][j], 0, 0, 0);
    __syncthreads();
  }
  int rg = lane >> 4;
  #pragma unroll
  for (int i = 0; i < 4; ++i) {
    #pragma unroll
    for (int j = 0; j < 4; ++j) {
      int col = bn + wn + j*16 + l16;
      #pragma unroll
      for (int r = 0; r < 4; ++r) {
        int row = bm + wm + i*16 + rg*4 + r;
        float v = acc[i][j][r];
        if (col < nsplit) C0[(size_t)row*ld0 + col] = v;
        else              C1[(size_t)row*ld1 + (col - nsplit)] = v;
      }
    }
  }
}

// ---------------- f32 tiled GEMM (for the small N=104 projection) ----------------
__global__ __launch_bounds__(256) void gemm_f32(const float* __restrict__ A,
    const float* __restrict__ B, float* __restrict__ C, int M, int N, int K)
{
  __shared__ float As[16][64];
  __shared__ float Bs[16][64];
  int tid = threadIdx.x;
  int bm = blockIdx.y * 64, bn = blockIdx.x * 64;
  int tx = tid & 15, ty = tid >> 4;
  int am = tid >> 2, ak = (tid & 3) << 2;
  int bk = tid >> 4, bn4 = (tid & 15) << 2;
  float acc[4][4] = {};
  for (int k0 = 0; k0 < K; k0 += 16) {
    float4 a4 = *(const float4*)&A[(size_t)(bm+am)*K + k0 + ak];
    As[ak+0][am] = a4.x; As[ak+1][am] = a4.y; As[ak+2][am] = a4.z; As[ak+3][am] = a4.w;
    float4 b4;
    int col = bn + bn4;
    if (col + 3 < N) {
      b4 = *(const float4*)&B[(size_t)(k0+bk)*N + col];
    } else {
      const float* bp = &B[(size_t)(k0+bk)*N];
      b4.x = (col+0<N)? bp[col+0]:0.f; b4.y = (col+1<N)? bp[col+1]:0.f;
      b4.z = (col+2<N)? bp[col+2]:0.f; b4.w = (col+3<N)? bp[col+3]:0.f;
    }
    *(float4*)&Bs[bk][bn4] = b4;
    __syncthreads();
    #pragma unroll
    for (int kk = 0; kk < 16; ++kk) {
      float4 av = *(const float4*)&As[kk][ty<<2];
      float4 bv = *(const float4*)&Bs[kk][tx<<2];
      float a_[4] = {av.x,av.y,av.z,av.w};
      float b_[4] = {bv.x,bv.y,bv.z,bv.w};
      #pragma unroll
      for (int i2 = 0; i2 < 4; ++i2)
        #pragma unroll
        for (int j2 = 0; j2 < 4; ++j2)
          acc[i2][j2] += a_[i2]*b_[j2];
    }
    __syncthreads();
  }
  #pragma unroll
  for (int i2 = 0; i2 < 4; ++i2) {
    int row = bm + (ty<<2) + i2;
    #pragma unroll
    for (int j2 = 0; j2 < 4; ++j2) {
      int col = bn + (tx<<2) + j2;
      if (col < N) C[(size_t)row*N + col] = acc[i2][j2];
    }
  }
}

// -------- depthwise causal conv(4) + silu, optional per-head l2norm --------
__global__ __launch_bounds__(256) void conv_silu(const float* __restrict__ X,
    const float* __restrict__ W, float* __restrict__ Y, int mode, int ldx)
{
  int row = blockIdx.x;
  int b = row >> 10, t = row & 1023;
  int tid = threadIdx.x;
  int c0 = tid << 2;
  float w[4][4];
  #pragma unroll
  for (int c = 0; c < 4; ++c) {
    float4 wv = *(const float4*)&W[(c0 + c)*4];
    w[c][0]=wv.x; w[c][1]=wv.y; w[c][2]=wv.z; w[c][3]=wv.w;
  }
  float acc[4] = {0.f,0.f,0.f,0.f};
  #pragma unroll
  for (int j = 0; j < 4; ++j) {
    int tt = t - 3 + j;
    if (tt >= 0) {
      float4 xv = *(const float4*)&X[(size_t)(b*1024 + tt)*ldx + c0];
      acc[0] += w[0][j]*xv.x; acc[1] += w[1][j]*xv.y;
      acc[2] += w[2][j]*xv.z; acc[3] += w[3][j]*xv.w;
    }
  }
  #pragma unroll
  for (int c = 0; c < 4; ++c) acc[c] *= sigm(acc[c]);
  if (mode < 2) {
    float ss = acc[0]*acc[0]+acc[1]*acc[1]+acc[2]*acc[2]+acc[3]*acc[3];
    ss += __shfl_xor(ss, 1); ss += __shfl_xor(ss, 2); ss += __shfl_xor(ss, 4);
    ss += __shfl_xor(ss, 8); ss += __shfl_xor(ss, 16);
    float r = rsqrtf(ss + 1e-6f);
    if (mode == 0) r *= SCALE_Q;
    acc[0]*=r; acc[1]*=r; acc[2]*=r; acc[3]*=r;
  }
  float4 yv; yv.x=acc[0]; yv.y=acc[1]; yv.z=acc[2]; yv.w=acc[3];
  *(float4*)&Y[(size_t)(b*1024 + t)*1024 + c0] = yv;
}

// -------- per-(b,h) log-decay cumsum, one block per bh --------
__global__ __launch_bounds__(256) void gc2(const float* __restrict__ xs,
    const float* __restrict__ A_log, const float* __restrict__ dt_bias,
    float* __restrict__ gc)
{
  int bh = blockIdx.x, b = bh >> 3, h = bh & 7;
  __shared__ float sc[256];
  int tid = threadIdx.x;
  float aexp = __expf(A_log[h]), db = dt_bias[h];
  int t0 = tid*4;
  float g[4], csum = 0.f;
  #pragma unroll
  for (int z = 0; z < 4; ++z) {
    float zv = xs[(size_t)(b*1024 + t0 + z)*104 + 8 + h] + db;
    float sp = (zv > 20.f) ? zv : log1pf(__expf(zv));
    csum += -aexp*sp;
    g[z] = csum;
  }
  sc[tid] = csum;
  __syncthreads();
  for (int ofs = 1; ofs < 256; ofs <<= 1) {
    float v = (tid >= ofs) ? sc[tid-ofs] : 0.f;
    __syncthreads();
    sc[tid] += v;
    __syncthreads();
  }
  float excl = sc[tid] - csum;
  #pragma unroll
  for (int z = 0; z < 4; ++z) gc[bh*1024 + t0 + z] = excl + g[z];
}

// -------- chunk prep: per (bh,chunk of 64): A, in-register fwd substitution --------
// emits w = L^-1(beta v), Wk = L^-1(beta e^{gc-gca} K), Kp = e^{gcnext-gc} K, eD
__global__ __launch_bounds__(256) void chunk_prep(const float* __restrict__ Kg,
    const float* __restrict__ Vg, const float* __restrict__ xs,
    const float* __restrict__ gcg, float* __restrict__ cw, float* __restrict__ cWk,
    float* __restrict__ cKp, float* __restrict__ eD)
{
  int blk = blockIdx.x;
  int bh = blk >> 4, ck = blk & 15;
  int b = bh >> 3, h = bh & 7;
  int a = ck << 6;
  __shared__ float Kc[64][132];
  __shared__ float As[64][68];
  __shared__ float gcl[65];
  __shared__ float bl[64];
  __shared__ float egc[64];
  __shared__ float edt[64];
  int tid = threadIdx.x;
  for (int e = tid; e < 64*32; e += 256) {
    int t = e >> 5, c4 = (e & 31) << 2;
    *(float4*)&Kc[t][c4] = *(const float4*)&Kg[(size_t)(b*1024 + a + t)*1024 + h*128 + c4];
  }
  if (tid < 64) {
    gcl[tid] = gcg[bh*1024 + a + tid];
    bl[tid] = sigm(xs[(size_t)(b*1024 + a + tid)*104 + h]);
  }
  if (tid == 64) gcl[64] = (ck < 15) ? gcg[bh*1024 + a + 64] : 0.f;
  __syncthreads();
  if (tid < 64) {
    egc[tid] = __expf(gcl[tid] - gcl[0]);
    edt[tid] = (ck < 15) ? __expf(gcl[64] - gcl[tid]) : 0.f;
  }
  {
    int ti = tid >> 4, si = tid & 15;
    if (si <= ti) {
      float dot[4][4] = {};
      for (int kk = 0; kk < 128; kk += 4) {
        float4 kt[4], ks[4];
        #pragma unroll
        for (int z = 0; z < 4; ++z) kt[z] = *(float4*)&Kc[ti*4+z][kk];
        #pragma unroll
        for (int z = 0; z < 4; ++z) ks[z] = *(float4*)&Kc[si*4+z][kk];
        #pragma unroll
        for (int i = 0; i < 4; ++i)
          #pragma unroll
          for (int j = 0; j < 4; ++j)
            dot[i][j] += kt[i].x*ks[j].x + kt[i].y*ks[j].y + kt[i].z*ks[j].z + kt[i].w*ks[j].w;
      }
      #pragma unroll
      for (int i = 0; i < 4; ++i) {
        int t = ti*4 + i;
        #pragma unroll
        for (int j = 0; j < 4; ++j) {
          int s = si*4 + j;
          if (s < t) As[t][s] = bl[t]*dot[i][j]*__expf(gcl[t]-gcl[s]);
        }
      }
    }
  }
  __syncthreads();
  // one column per thread: c<128 -> v-column, else k-column
  int c = tid;
  float u[64];
  if (c < 128) {
    #pragma unroll
    for (int t = 0; t < 64; ++t)
      u[t] = bl[t]*Vg[(size_t)(b*1024 + a + t)*1024 + h*128 + c];
  } else {
    int d = c - 128;
    #pragma unroll
    for (int t = 0; t < 64; ++t)
      u[t] = bl[t]*egc[t]*Kc[t][d];
  }
  #pragma unroll
  for (int t = 1; t < 64; ++t) {
    float acc = u[t];
    int s = 0;
    #pragma unroll
    for (; s + 4 <= t; s += 4) {
      float4 a4 = *(float4*)&As[t][s];
      acc -= a4.x*u[s] + a4.y*u[s+1] + a4.z*u[s+2] + a4.w*u[s+3];
    }
    #pragma unroll
    for (; s < t; ++s) acc -= As[t][s]*u[s];
    u[t] = acc;
  }
  size_t cbase = (size_t)blk*8192;
  if (c < 128) {
    #pragma unroll
    for (int t = 0; t < 64; ++t)
      cw[cbase + t*128 + c] = u[t];
  } else {
    int d = c - 128;
    #pragma unroll
    for (int t = 0; t < 64; ++t) {
      cWk[cbase + t*128 + d] = u[t];
      cKp[cbase + t*128 + d] = Kc[t][d]*edt[t];
    }
  }
  if (tid == 0) eD[blk] = (ck < 15) ? __expf(gcl[64]-gcl[0]) : 0.f;
}

// -------- chunk scan: 64 blocks = (dv-quarter, bh); 16 serial steps of 2 matmuls --------
__global__ __launch_bounds__(256) void chunk_scan(const float* __restrict__ cw,
    const float* __restrict__ cWk, const float* __restrict__ cKp,
    const float* __restrict__ eD, float* __restrict__ Ug)
{
  int blk = blockIdx.x;
  int eg = blk >> 4, bh = blk & 15;     // blocks of same bh land on same XCD (stride 16)
  int b = bh >> 3, h = bh & 7;
  int e_base = eg * 32;
  __shared__ float S[128][36];
  __shared__ float Wks[64][132];
  __shared__ float Kps[64][132];
  __shared__ float us[64][36];
  int tid = threadIdx.x;
  for (int e = tid; e < 128*9; e += 256) {
    int r = e/9, c4 = (e%9)*4;
    *(f32x4*)&S[r][c4] = (f32x4){0.f,0.f,0.f,0.f};
  }
  for (int i = 0; i < 16; ++i) {
    int ci = bh*16 + i, a = i*64;
    const float* wk = cWk + (size_t)ci*8192;
    const float* kp = cKp + (size_t)ci*8192;
    for (int e = tid; e < 64*32; e += 256) {
      int t = e >> 5, c4 = (e & 31) << 2;
      *(float4*)&Wks[t][c4] = *(const float4*)&wk[t*128 + c4];
      *(float4*)&Kps[t][c4] = *(const float4*)&kp[t*128 + c4];
    }
    __syncthreads();
    // u = w - Wk @ S : thread tile 2t x 4e
    {
      int tq = tid >> 3, e0 = (tid & 7) << 2;
      int t0 = tq*2;
      const float* wrow = cw + (size_t)ci*8192;
      f32x4 acc0 = *(const f32x4*)&wrow[t0*128 + e_base + e0];
      f32x4 acc1 = *(const f32x4*)&wrow[(t0+1)*128 + e_base + e0];
      for (int kk = 0; kk < 128; kk += 4) {
        f32x4 w0 = *(f32x4*)&Wks[t0][kk];
        f32x4 w1 = *(f32x4*)&Wks[t0+1][kk];
        f32x4 s0 = *(f32x4*)&S[kk][e0];
        f32x4 s1 = *(f32x4*)&S[kk+1][e0];
        f32x4 s2 = *(f32x4*)&S[kk+2][e0];
        f32x4 s3 = *(f32x4*)&S[kk+3][e0];
        acc0 -= w0[0]*s0; acc0 -= w0[1]*s1; acc0 -= w0[2]*s2; acc0 -= w0[3]*s3;
        acc1 -= w1[0]*s0; acc1 -= w1[1]*s1; acc1 -= w1[2]*s2; acc1 -= w1[3]*s3;
      }
      *(f32x4*)&us[t0][e0] = acc0;
      *(f32x4*)&us[t0+1][e0] = acc1;
      size_t gr = (size_t)(b*1024 + a);
      *(f32x4*)&Ug[(gr+t0)*1024 + h*128 + e_base + e0] = acc0;
      *(f32x4*)&Ug[(gr+t0+1)*1024 + h*128 + e_base + e0] = acc1;
    }
    __syncthreads();
    // S = eD*S + Kp^T @ u : thread tile 4kk x 4e
    if (i < 15) {
      float ed = eD[ci];
      int kq = tid >> 3, e0 = (tid & 7) << 2;
      int kk0 = kq*4;
      f32x4 sa[4];
      #pragma unroll
      for (int z = 0; z < 4; ++z) sa[z] = ed * *(f32x4*)&S[kk0+z][e0];
      for (int t = 0; t < 64; ++t) {
        f32x4 kp4 = *(f32x4*)&Kps[t][kk0];
        f32x4 u4 = *(f32x4*)&us[t][e0];
        #pragma unroll
        for (int z = 0; z < 4; ++z) sa[z] += kp4[z]*u4;
      }
      #pragma unroll
      for (int z = 0; z < 4; ++z) *(f32x4*)&S[kk0+z][e0] = sa[z];
    }
    __syncthreads();
  }
}

// -------- log-linear readout: o = ((q k^T) * exp(dgc) * lam[level]) @ u --------
__global__ __launch_bounds__(256) void readout(const float* __restrict__ Qg,
    const float* __restrict__ Kg, const float* __restrict__ Ug,
    const float* __restrict__ gcg, const float* __restrict__ xs,
    float* __restrict__ Og)
{
  int blk = blockIdx.x;
  int bh = blk >> 5, ic = blk & 31;
  int b = bh >> 3, h = bh & 7;
  int a = ic << 5;
  __shared__ float Qc[32][129];
  __shared__ float KU[32][129];
  __shared__ float P[32][33];
  __shared__ float lamS[32][11];
  __shared__ float gct[32], gcs[32];
  int tid = threadIdx.x;
  for (int e = tid; e < 32*128; e += 256) {
    int t = e >> 7, kk = e & 127;
    Qc[t][kk] = Qg[(size_t)(b*1024 + a + t)*1024 + h*128 + kk];
  }
  if (tid < 32) gct[tid] = gcg[bh*1024 + a + tid];
  for (int e = tid; e < 32*11; e += 256) {
    int t = e / 11, l = e % 11;
    lamS[t][l] = sigm(xs[(size_t)(b*1024 + a + t)*104 + 16 + h*11 + l]);
  }
  float acc[16] = {};
  int rt = tid >> 3;
  int ps0 = (tid & 7) << 2;
  int udq = (tid & 7) << 4;
  for (int j = 0; j <= ic; ++j) {
    int s0 = j << 5;
    __syncthreads();
    for (int e = tid; e < 32*128; e += 256) {
      int s = e >> 7, kk = e & 127;
      KU[s][kk] = Kg[(size_t)(b*1024 + s0 + s)*1024 + h*128 + kk];
    }
    if (tid < 32) gcs[tid] = gcg[bh*1024 + s0 + tid];
    __syncthreads();
    {
      float dot[4] = {0.f,0.f,0.f,0.f};
      for (int kk = 0; kk < 128; ++kk) {
        float qv = Qc[rt][kk];
        dot[0] += qv * KU[ps0+0][kk];
        dot[1] += qv * KU[ps0+1][kk];
        dot[2] += qv * KU[ps0+2][kk];
        dot[3] += qv * KU[ps0+3][kk];
      }
      int tg = a + rt;
      #pragma unroll
      for (int c = 0; c < 4; ++c) {
        int sg = s0 + ps0 + c;
        float pv = 0.f;
        if (sg <= tg) {
          int lev = 31 - __clz((unsigned)((tg+1) ^ sg));
          lev = lev > 10 ? 10 : lev;
          pv = dot[c] * __expf(gct[rt] - gcs[ps0+c]) * lamS[rt][lev];
        }
        P[rt][ps0+c] = pv;
      }
    }
    __syncthreads();
    for (int e = tid; e < 32*128; e += 256) {
      int s = e >> 7, kk = e & 127;
      KU[s][kk] = Ug[(size_t)(b*1024 + s0 + s)*1024 + h*128 + kk];
    }
    __syncthreads();
    for (int s = 0; s < 32; ++s) {
      float p = P[rt][s];
      #pragma unroll
      for (int c = 0; c < 16; ++c) acc[c] += p * KU[s][udq + c];
    }
  }
  #pragma unroll
  for (int c = 0; c < 16; ++c)
    Og[(size_t)(b*1024 + a + rt)*1024 + h*128 + udq + c] = acc[c];
}

// -------- gated RMSNorm -> bf16 --------
__global__ __launch_bounds__(64) void normgate(const float* __restrict__ O,
    const float* __restrict__ G, const float* __restrict__ norm_w,
    ushort* __restrict__ Y)
{
  int row = blockIdx.x;
  int lane = threadIdx.x;
  size_t base = (size_t)(row >> 3)*1024 + (size_t)(row & 7)*128;
  float2 o = *(const float2*)&O[base + lane*2];
  float ss = o.x*o.x + o.y*o.y;
  #pragma unroll
  for (int m = 1; m < 64; m <<= 1) ss += __shfl_xor(ss, m);
  float r = rsqrtf(ss * (1.f/128.f) + 1e-5f);
  float2 g = *(const float2*)&G[base + lane*2];
  ushort2 y;
  y.x = f2b(o.x * r * norm_w[lane*2+0] * (g.x * sigm(g.x)));
  y.y = f2b(o.y * r * norm_w[lane*2+1] * (g.y * sigm(g.y)));
  *(ushort2*)&Y[base + lane*2] = y;
}

extern "C" void kernel_launch(void* const* d_in, const int* in_sizes, int n_in,
                              void* d_out, int out_size, void* d_ws, size_t ws_size,
                              hipStream_t stream)
{
  const float* x    = (const float*)d_in[0];
  const float* Wq   = (const float*)d_in[3];
  const float* Wk   = (const float*)d_in[4];
  const float* Wv   = (const float*)d_in[5];
  const float* Wb   = (const float*)d_in[6];
  const float* Wa   = (const float*)d_in[7];
  const float* Wl   = (const float*)d_in[8];
  const float* Wg   = (const float*)d_in[9];
  const float* Wo   = (const float*)d_in[10];
  const float* cq   = (const float*)d_in[11];
  const float* ck   = (const float*)d_in[12];
  const float* cv   = (const float*)d_in[13];
  const float* A_log   = (const float*)d_in[14];
  const float* dt_bias = (const float*)d_in[15];
  const float* norm_w  = (const float*)d_in[16];
  float* out = (float*)d_out;

  float* p = (float*)d_ws;
  float* xqkv = p;  p += 6291456;            // [2048][3072] f32 (dead after convs)
  float* xg   = p;  p += 2097152;            // [2048][1024]
  float* qb   = p;  p += 2097152;
  float* kb   = p;  p += 2097152;
  float* vb   = p;  p += 2097152;
  float* ub   = p;  p += 2097152;
  float* ob   = p;  p += 2097152;
  float* xs   = p;  p += 212992;             // [2048][104]
  float* gc   = p;  p += 16384;              // [16][1024]
  float* eD   = p;  p += 256;
  ushort* x16 = (ushort*)p; p += 1048576;    // [2048][1024] bf16
  ushort* Wt4 = (ushort*)p; p += 2097152;    // [4096][1024] bf16
  ushort* Wot = (ushort*)p; p += 524288;     // [1024][1024] bf16
  float* Wsm  = p;  p += 106496;             // [1024][104]
  ushort* yb16= (ushort*)p; p += 1048576;    // [2048][1024] bf16
  // chunk buffers overlay the dead xqkv region (24MB): w,Wk,Kp each [256][64][128] f32
  float* cw  = xqkv;
  float* cWk = xqkv + 2097152;
  float* cKp = xqkv + 4194304;

  dim3 blk(256);
  cast_x<<<dim3(2048), blk, 0, stream>>>(x, x16);
  transcast<<<dim3(32,32), blk, 0, stream>>>(Wq, Wt4);
  transcast<<<dim3(32,32), blk, 0, stream>>>(Wk, Wt4 + 1024*1024);
  transcast<<<dim3(32,32), blk, 0, stream>>>(Wv, Wt4 + 2*1024*1024);
  transcast<<<dim3(32,32), blk, 0, stream>>>(Wg, Wt4 + 3*1024*1024);
  transcast<<<dim3(32,32), blk, 0, stream>>>(Wo, Wot);
  copy_wsmall<<<dim3(416), blk, 0, stream>>>(Wb, Wa, Wl, Wsm);
  // fused q|k|v|g projection: cols 0..3071 -> xqkv, 3072..4095 -> xg
  gemm_bf16<<<dim3(32,16), blk, 0, stream>>>(x16, Wt4, xqkv, xg, 2048, 4096, 1024,
                                             3072, 3072, 1024);
  gemm_f32<<<dim3(2,32), blk, 0, stream>>>(x, Wsm, xs, 2048, 104, 1024);
  conv_silu<<<dim3(2048), blk, 0, stream>>>(xqkv + 0,    cq, qb, 0, 3072);
  conv_silu<<<dim3(2048), blk, 0, stream>>>(xqkv + 1024, ck, kb, 1, 3072);
  conv_silu<<<dim3(2048), blk, 0, stream>>>(xqkv + 2048, cv, vb, 2, 3072);
  gc2<<<dim3(16), blk, 0, stream>>>(xs, A_log, dt_bias, gc);
  chunk_prep<<<dim3(256), blk, 0, stream>>>(kb, vb, xs, gc, cw, cWk, cKp, eD);
  chunk_scan<<<dim3(64), blk, 0, stream>>>(cw, cWk, cKp, eD, ub);
  readout<<<dim3(512), blk, 0, stream>>>(qb, kb, ub, gc, xs, ob);
  normgate<<<dim3(16384), dim3(64), 0, stream>>>(ob, xg, norm_w, yb16);
  gemm_bf16<<<dim3(8,16), blk, 0, stream>>>(yb16, Wot, out, out, 2048, 1024, 1024,
                                            1024, 1024, 1024);
}

// Round 4
// 393.785 us; speedup vs baseline: 6.2358x; 2.3746x over previous
//
#include <hip/hip_runtime.h>
#include <hip/hip_bf16.h>
#include <math.h>

// B=2, T=1024, D=1024, H=8, Dh=128, L=11, conv=4; chunk C=64, 16 chunks/bh
#define SCALE_Q 0.08838834764831845f

typedef __bf16 bf16x8 __attribute__((ext_vector_type(8)));
typedef float f32x4 __attribute__((ext_vector_type(4)));

static __device__ __forceinline__ float sigm(float x){ return 1.f/(1.f+__expf(-x)); }
static __device__ __forceinline__ ushort f2b(float v){
  __hip_bfloat16 t = __float2bfloat16(v);
  return __builtin_bit_cast(ushort, t);
}

// ---------------- cast x f32 -> bf16 ----------------
__global__ __launch_bounds__(256) void cast_x(const float* __restrict__ X,
    ushort* __restrict__ Y)
{
  int idx = blockIdx.x*256 + threadIdx.x;
  float4 v = *(const float4*)&X[(size_t)idx*4];
  ushort4 o; o.x=f2b(v.x); o.y=f2b(v.y); o.z=f2b(v.z); o.w=f2b(v.w);
  *(ushort4*)&Y[(size_t)idx*4] = o;
}

// ---------------- transpose + cast: Wt[n][k] = bf16(W[k][n]), 1024x1024 ----------------
__global__ __launch_bounds__(256) void transcast(const float* __restrict__ W,
    ushort* __restrict__ Wt)
{
  __shared__ float tile[32][36];
  int n0 = blockIdx.x*32, k0 = blockIdx.y*32;
  int tid = threadIdx.x;
  int r = tid >> 3, c4 = (tid & 7) << 2;
  *(float4*)&tile[r][c4] = *(const float4*)&W[(size_t)(k0 + r)*1024 + n0 + c4];
  __syncthreads();
  ushort4 o;
  o.x = f2b(tile[c4+0][r]); o.y = f2b(tile[c4+1][r]);
  o.z = f2b(tile[c4+2][r]); o.w = f2b(tile[c4+3][r]);
  *(ushort4*)&Wt[(size_t)(n0 + r)*1024 + k0 + c4] = o;
}

// ---------------- concat small weights: Wsm[k][0:8]=Wb, [8:16]=Wa, [16:104]=Wl ----------------
__global__ __launch_bounds__(256) void copy_wsmall(const float* __restrict__ Wb,
    const float* __restrict__ Wa, const float* __restrict__ Wl, float* __restrict__ Wsm)
{
  int idx = blockIdx.x*256 + threadIdx.x;
  if (idx >= 1024*104) return;
  int k = idx / 104, c = idx % 104;
  float v = (c < 8) ? Wb[k*8+c] : (c < 16) ? Wa[k*8+(c-8)] : Wl[k*88+(c-16)];
  Wsm[idx] = v;
}

// ---------------- bf16 MFMA GEMM: C[M,N] = A[M,K] @ Bt[N,K]^T, C f32, split cols ----------------
__global__ __launch_bounds__(256) void gemm_bf16(const ushort* __restrict__ A,
    const ushort* __restrict__ Bt, float* __restrict__ C0, float* __restrict__ C1,
    int M, int N, int K, int nsplit, int ld0, int ld1)
{
  __shared__ ushort As[128*32];
  __shared__ ushort Bs[128*32];
  int tid = threadIdx.x;
  int bm = blockIdx.y * 128, bn = blockIdx.x * 128;
  int wave = tid >> 6, lane = tid & 63;
  int wm = (wave >> 1) * 64, wn = (wave & 1) * 64;
  int l16 = lane & 15, kh = lane >> 4;
  f32x4 acc[4][4] = {};
  int rowA0 = tid >> 2, boA = (tid & 3) * 16;
  for (int k0 = 0; k0 < K; k0 += 32) {
    #pragma unroll
    for (int j = 0; j < 2; ++j) {
      int row = rowA0 + j*64;
      const char* gA = (const char*)A + (((size_t)(bm+row)*K + k0)*2 + boA);
      const char* gB = (const char*)Bt + (((size_t)(bn+row)*K + k0)*2 + boA);
      __builtin_amdgcn_global_load_lds((const __attribute__((address_space(1))) unsigned*)gA,
        (__attribute__((address_space(3))) unsigned*)((char*)As + row*64 + boA), 16, 0, 0);
      __builtin_amdgcn_global_load_lds((const __attribute__((address_space(1))) unsigned*)gB,
        (__attribute__((address_space(3))) unsigned*)((char*)Bs + row*64 + boA), 16, 0, 0);
    }
    __syncthreads();
    bf16x8 af[4], bfr[4];
    #pragma unroll
    for (int i = 0; i < 4; ++i)
      af[i] = *(bf16x8*)((char*)As + (wm + i*16 + l16)*64 + kh*16);
    #pragma unroll
    for (int j = 0; j < 4; ++j)
      bfr[j] = *(bf16x8*)((char*)Bs + (wn + j*16 + l16)*64 + kh*16);
    #pragma unroll
    for (int i = 0; i < 4; ++i)
      #pragma unroll
      for (int j = 0; j < 4; ++j)
        acc[i][j] = __builtin_amdgcn_mfma_f32_16x16x32_bf16(af[i], bfr[j], acc[i][j], 0, 0, 0);
    __syncthreads();
  }
  int rg = lane >> 4;
  #pragma unroll
  for (int i = 0; i < 4; ++i) {
    #pragma unroll
    for (int j = 0; j < 4; ++j) {
      int col = bn + wn + j*16 + l16;
      #pragma unroll
      for (int r = 0; r < 4; ++r) {
        int row = bm + wm + i*16 + rg*4 + r;
        float v = acc[i][j][r];
        if (col < nsplit) C0[(size_t)row*ld0 + col] = v;
        else              C1[(size_t)row*ld1 + (col - nsplit)] = v;
      }
    }
  }
}

// ---------------- f32 tiled GEMM (small N=104 projection) ----------------
__global__ __launch_bounds__(256) void gemm_f32(const float* __restrict__ A,
    const float* __restrict__ B, float* __restrict__ C, int M, int N, int K)
{
  __shared__ float As[16][64];
  __shared__ float Bs[16][64];
  int tid = threadIdx.x;
  int bm = blockIdx.y * 64, bn = blockIdx.x * 64;
  int tx = tid & 15, ty = tid >> 4;
  int am = tid >> 2, ak = (tid & 3) << 2;
  int bk = tid >> 4, bn4 = (tid & 15) << 2;
  float acc[4][4] = {};
  for (int k0 = 0; k0 < K; k0 += 16) {
    float4 a4 = *(const float4*)&A[(size_t)(bm+am)*K + k0 + ak];
    As[ak+0][am] = a4.x; As[ak+1][am] = a4.y; As[ak+2][am] = a4.z; As[ak+3][am] = a4.w;
    float4 b4;
    int col = bn + bn4;
    if (col + 3 < N) {
      b4 = *(const float4*)&B[(size_t)(k0+bk)*N + col];
    } else {
      const float* bp = &B[(size_t)(k0+bk)*N];
      b4.x = (col+0<N)? bp[col+0]:0.f; b4.y = (col+1<N)? bp[col+1]:0.f;
      b4.z = (col+2<N)? bp[col+2]:0.f; b4.w = (col+3<N)? bp[col+3]:0.f;
    }
    *(float4*)&Bs[bk][bn4] = b4;
    __syncthreads();
    #pragma unroll
    for (int kk = 0; kk < 16; ++kk) {
      float4 av = *(const float4*)&As[kk][ty<<2];
      float4 bv = *(const float4*)&Bs[kk][tx<<2];
      float a_[4] = {av.x,av.y,av.z,av.w};
      float b_[4] = {bv.x,bv.y,bv.z,bv.w};
      #pragma unroll
      for (int i2 = 0; i2 < 4; ++i2)
        #pragma unroll
        for (int j2 = 0; j2 < 4; ++j2)
          acc[i2][j2] += a_[i2]*b_[j2];
    }
    __syncthreads();
  }
  #pragma unroll
  for (int i2 = 0; i2 < 4; ++i2) {
    int row = bm + (ty<<2) + i2;
    #pragma unroll
    for (int j2 = 0; j2 < 4; ++j2) {
      int col = bn + (tx<<2) + j2;
      if (col < N) C[(size_t)row*N + col] = acc[i2][j2];
    }
  }
}

// -------- depthwise causal conv(4) + silu (+ optional l2norm); f32 and/or bf16 out --------
__global__ __launch_bounds__(256) void conv_silu(const float* __restrict__ X,
    const float* __restrict__ W, float* __restrict__ Yf, ushort* __restrict__ Yb,
    int mode, int ldx)
{
  int row = blockIdx.x;
  int b = row >> 10, t = row & 1023;
  int tid = threadIdx.x;
  int c0 = tid << 2;
  float w[4][4];
  #pragma unroll
  for (int c = 0; c < 4; ++c) {
    float4 wv = *(const float4*)&W[(c0 + c)*4];
    w[c][0]=wv.x; w[c][1]=wv.y; w[c][2]=wv.z; w[c][3]=wv.w;
  }
  float acc[4] = {0.f,0.f,0.f,0.f};
  #pragma unroll
  for (int j = 0; j < 4; ++j) {
    int tt = t - 3 + j;
    if (tt >= 0) {
      float4 xv = *(const float4*)&X[(size_t)(b*1024 + tt)*ldx + c0];
      acc[0] += w[0][j]*xv.x; acc[1] += w[1][j]*xv.y;
      acc[2] += w[2][j]*xv.z; acc[3] += w[3][j]*xv.w;
    }
  }
  #pragma unroll
  for (int c = 0; c < 4; ++c) acc[c] *= sigm(acc[c]);
  if (mode < 2) {
    float ss = acc[0]*acc[0]+acc[1]*acc[1]+acc[2]*acc[2]+acc[3]*acc[3];
    ss += __shfl_xor(ss, 1); ss += __shfl_xor(ss, 2); ss += __shfl_xor(ss, 4);
    ss += __shfl_xor(ss, 8); ss += __shfl_xor(ss, 16);
    float r = rsqrtf(ss + 1e-6f);
    if (mode == 0) r *= SCALE_Q;
    acc[0]*=r; acc[1]*=r; acc[2]*=r; acc[3]*=r;
  }
  size_t o = (size_t)(b*1024 + t)*1024 + c0;
  if (mode != 0) {
    float4 yv; yv.x=acc[0]; yv.y=acc[1]; yv.z=acc[2]; yv.w=acc[3];
    *(float4*)&Yf[o] = yv;
  }
  if (mode != 2) {
    ushort4 yb; yb.x=f2b(acc[0]); yb.y=f2b(acc[1]); yb.z=f2b(acc[2]); yb.w=f2b(acc[3]);
    *(ushort4*)&Yb[o] = yb;
  }
}

// -------- per-(b,h) log-decay cumsum, one block per bh --------
__global__ __launch_bounds__(256) void gc2(const float* __restrict__ xs,
    const float* __restrict__ A_log, const float* __restrict__ dt_bias,
    float* __restrict__ gc)
{
  int bh = blockIdx.x, b = bh >> 3, h = bh & 7;
  __shared__ float sc[256];
  int tid = threadIdx.x;
  float aexp = __expf(A_log[h]), db = dt_bias[h];
  int t0 = tid*4;
  float g[4], csum = 0.f;
  #pragma unroll
  for (int z = 0; z < 4; ++z) {
    float zv = xs[(size_t)(b*1024 + t0 + z)*104 + 8 + h] + db;
    float sp = (zv > 20.f) ? zv : log1pf(__expf(zv));
    csum += -aexp*sp;
    g[z] = csum;
  }
  sc[tid] = csum;
  __syncthreads();
  for (int ofs = 1; ofs < 256; ofs <<= 1) {
    float v = (tid >= ofs) ? sc[tid-ofs] : 0.f;
    __syncthreads();
    sc[tid] += v;
    __syncthreads();
  }
  float excl = sc[tid] - csum;
  #pragma unroll
  for (int z = 0; z < 4; ++z) gc[bh*1024 + t0 + z] = excl + g[z];
}

// -------- chunk prep: per (bh,chunk of 64): A, in-register fwd substitution --------
__global__ __launch_bounds__(256) void chunk_prep(const float* __restrict__ Kg,
    const float* __restrict__ Vg, const float* __restrict__ xs,
    const float* __restrict__ gcg, float* __restrict__ cw, float* __restrict__ cWk,
    float* __restrict__ cKp, float* __restrict__ eD)
{
  int blk = blockIdx.x;
  int bh = blk >> 4, ck = blk & 15;
  int b = bh >> 3, h = bh & 7;
  int a = ck << 6;
  __shared__ float Kc[64][132];
  __shared__ float As[64][68];
  __shared__ float gcl[65];
  __shared__ float bl[64];
  __shared__ float egc[64];
  __shared__ float edt[64];
  int tid = threadIdx.x;
  for (int e = tid; e < 64*32; e += 256) {
    int t = e >> 5, c4 = (e & 31) << 2;
    *(float4*)&Kc[t][c4] = *(const float4*)&Kg[(size_t)(b*1024 + a + t)*1024 + h*128 + c4];
  }
  if (tid < 64) {
    gcl[tid] = gcg[bh*1024 + a + tid];
    bl[tid] = sigm(xs[(size_t)(b*1024 + a + tid)*104 + h]);
  }
  if (tid == 64) gcl[64] = (ck < 15) ? gcg[bh*1024 + a + 64] : 0.f;
  __syncthreads();
  if (tid < 64) {
    egc[tid] = __expf(gcl[tid] - gcl[0]);
    edt[tid] = (ck < 15) ? __expf(gcl[64] - gcl[tid]) : 0.f;
  }
  {
    int ti = tid >> 4, si = tid & 15;
    if (si <= ti) {
      float dot[4][4] = {};
      for (int kk = 0; kk < 128; kk += 4) {
        float4 kt[4], ks[4];
        #pragma unroll
        for (int z = 0; z < 4; ++z) kt[z] = *(float4*)&Kc[ti*4+z][kk];
        #pragma unroll
        for (int z = 0; z < 4; ++z) ks[z] = *(float4*)&Kc[si*4+z][kk];
        #pragma unroll
        for (int i = 0; i < 4; ++i)
          #pragma unroll
          for (int j = 0; j < 4; ++j)
            dot[i][j] += kt[i].x*ks[j].x + kt[i].y*ks[j].y + kt[i].z*ks[j].z + kt[i].w*ks[j].w;
      }
      #pragma unroll
      for (int i = 0; i < 4; ++i) {
        int t = ti*4 + i;
        #pragma unroll
        for (int j = 0; j < 4; ++j) {
          int s = si*4 + j;
          if (s < t) As[t][s] = bl[t]*dot[i][j]*__expf(gcl[t]-gcl[s]);
        }
      }
    }
  }
  __syncthreads();
  int c = tid;
  float u[64];
  if (c < 128) {
    #pragma unroll
    for (int t = 0; t < 64; ++t)
      u[t] = bl[t]*Vg[(size_t)(b*1024 + a + t)*1024 + h*128 + c];
  } else {
    int d = c - 128;
    #pragma unroll
    for (int t = 0; t < 64; ++t)
      u[t] = bl[t]*egc[t]*Kc[t][d];
  }
  #pragma unroll
  for (int t = 1; t < 64; ++t) {
    float acc = u[t];
    int s = 0;
    #pragma unroll
    for (; s + 4 <= t; s += 4) {
      float4 a4 = *(float4*)&As[t][s];
      acc -= a4.x*u[s] + a4.y*u[s+1] + a4.z*u[s+2] + a4.w*u[s+3];
    }
    #pragma unroll
    for (; s < t; ++s) acc -= As[t][s]*u[s];
    u[t] = acc;
  }
  size_t cbase = (size_t)blk*8192;
  if (c < 128) {
    #pragma unroll
    for (int t = 0; t < 64; ++t)
      cw[cbase + t*128 + c] = u[t];
  } else {
    int d = c - 128;
    #pragma unroll
    for (int t = 0; t < 64; ++t) {
      cWk[cbase + t*128 + d] = u[t];
      cKp[cbase + t*128 + d] = Kc[t][d]*edt[t];
    }
  }
  if (tid == 0) eD[blk] = (ck < 15) ? __expf(gcl[64]-gcl[0]) : 0.f;
}

// -------- chunk scan: 64 blocks = (dv-quarter, bh); emits u transposed bf16 Ut[d][t] --------
__global__ __launch_bounds__(256) void chunk_scan(const float* __restrict__ cw,
    const float* __restrict__ cWk, const float* __restrict__ cKp,
    const float* __restrict__ eD, ushort* __restrict__ Ut)
{
  int blk = blockIdx.x;
  int eg = blk >> 4, bh = blk & 15;
  int e_base = eg * 32;
  __shared__ float S[128][36];
  __shared__ float Wks[64][132];
  __shared__ float Kps[64][132];
  __shared__ float us[64][36];
  int tid = threadIdx.x;
  for (int e = tid; e < 128*9; e += 256) {
    int r = e/9, c4 = (e%9)*4;
    *(f32x4*)&S[r][c4] = (f32x4){0.f,0.f,0.f,0.f};
  }
  for (int i = 0; i < 16; ++i) {
    int ci = bh*16 + i, a = i*64;
    const float* wk = cWk + (size_t)ci*8192;
    const float* kp = cKp + (size_t)ci*8192;
    for (int e = tid; e < 64*32; e += 256) {
      int t = e >> 5, c4 = (e & 31) << 2;
      *(float4*)&Wks[t][c4] = *(const float4*)&wk[t*128 + c4];
      *(float4*)&Kps[t][c4] = *(const float4*)&kp[t*128 + c4];
    }
    __syncthreads();
    {
      int tq = tid >> 3, e0 = (tid & 7) << 2;
      int t0 = tq*2;
      const float* wrow = cw + (size_t)ci*8192;
      f32x4 acc0 = *(const f32x4*)&wrow[t0*128 + e_base + e0];
      f32x4 acc1 = *(const f32x4*)&wrow[(t0+1)*128 + e_base + e0];
      for (int kk = 0; kk < 128; kk += 4) {
        f32x4 w0 = *(f32x4*)&Wks[t0][kk];
        f32x4 w1 = *(f32x4*)&Wks[t0+1][kk];
        f32x4 s0 = *(f32x4*)&S[kk][e0];
        f32x4 s1 = *(f32x4*)&S[kk+1][e0];
        f32x4 s2 = *(f32x4*)&S[kk+2][e0];
        f32x4 s3 = *(f32x4*)&S[kk+3][e0];
        acc0 -= w0[0]*s0; acc0 -= w0[1]*s1; acc0 -= w0[2]*s2; acc0 -= w0[3]*s3;
        acc1 -= w1[0]*s0; acc1 -= w1[1]*s1; acc1 -= w1[2]*s2; acc1 -= w1[3]*s3;
      }
      *(f32x4*)&us[t0][e0] = acc0;
      *(f32x4*)&us[t0+1][e0] = acc1;
      #pragma unroll
      for (int z = 0; z < 4; ++z) {
        ushort2 w2; w2.x = f2b(acc0[z]); w2.y = f2b(acc1[z]);
        *(ushort2*)&Ut[(size_t)(bh*128 + e_base + e0 + z)*1024 + a + t0] = w2;
      }
    }
    __syncthreads();
    if (i < 15) {
      float ed = eD[ci];
      int kq = tid >> 3, e0 = (tid & 7) << 2;
      int kk0 = kq*4;
      f32x4 sa[4];
      #pragma unroll
      for (int z = 0; z < 4; ++z) sa[z] = ed * *(f32x4*)&S[kk0+z][e0];
      for (int t = 0; t < 64; ++t) {
        f32x4 kp4 = *(f32x4*)&Kps[t][kk0];
        f32x4 u4 = *(f32x4*)&us[t][e0];
        #pragma unroll
        for (int z = 0; z < 4; ++z) sa[z] += kp4[z]*u4;
      }
      #pragma unroll
      for (int z = 0; z < 4; ++z) *(f32x4*)&S[kk0+z][e0] = sa[z];
    }
    __syncthreads();
  }
}

// -------- MFMA log-linear readout --------
// grid (x: 16bh x 16 qchunks of 64, y: 2 s-halves). 4 waves x 16 q-rows.
__global__ __launch_bounds__(256) void readout2(const ushort* __restrict__ Qb,
    const ushort* __restrict__ Kb, const ushort* __restrict__ Ut,
    const float* __restrict__ gcg, const float* __restrict__ xs,
    float* __restrict__ Og)
{
  int blk = blockIdx.x;
  int bh = blk >> 4, ic = blk & 15;
  int half = blockIdx.y;
  int b = bh >> 3, h = bh & 7;
  int tbase = ic << 6;
  __shared__ ushort Pl[4][1024];       // 16x64 bf16 per wave, XOR-swizzled
  __shared__ float lamS[64][12];
  int tid = threadIdx.x;
  int wave = tid >> 6, lane = tid & 63;
  int l15 = lane & 15, kh = lane >> 4;
  for (int e = tid; e < 64*11; e += 256) {
    int t = e/11, l = e%11;
    lamS[t][l] = sigm(xs[(size_t)(b*1024+tbase+t)*104 + 16 + h*11 + l]);
  }
  int tl = kh*4;
  float gct_r[4];
  #pragma unroll
  for (int r = 0; r < 4; ++r) gct_r[r] = gcg[bh*1024 + tbase + wave*16 + tl + r];
  bf16x8 qf[4];
  {
    const ushort* qp = &Qb[(size_t)(b*1024 + tbase + wave*16 + l15)*1024 + h*128 + kh*8];
    #pragma unroll
    for (int kk = 0; kk < 4; ++kk) qf[kk] = *(const bf16x8*)(qp + kk*32);
  }
  __syncthreads();                     // lamS ready
  f32x4 accO[8] = {};
  int nsteps = ic + 1;
  int jmid = (nsteps + 1) >> 1;
  int j0 = half ? jmid : 0;
  int j1 = half ? nsteps : jmid;
  ushort* Pw = &Pl[wave][0];
  for (int j = j0; j < j1; ++j) {
    int sbase = j << 6;
    float gcs_r[4];
    #pragma unroll
    for (int jt = 0; jt < 4; ++jt)
      gcs_r[jt] = gcg[bh*1024 + sbase + jt*16 + l15];
    f32x4 accS[4] = {};
    #pragma unroll
    for (int jt = 0; jt < 4; ++jt) {
      const ushort* kp = &Kb[(size_t)(b*1024 + sbase + jt*16 + l15)*1024 + h*128 + kh*8];
      #pragma unroll
      for (int kk = 0; kk < 4; ++kk) {
        bf16x8 kf = *(const bf16x8*)(kp + kk*32);
        accS[jt] = __builtin_amdgcn_mfma_f32_16x16x32_bf16(qf[kk], kf, accS[jt], 0, 0, 0);
      }
    }
    #pragma unroll
    for (int jt = 0; jt < 4; ++jt) {
      int sg = sbase + jt*16 + l15;
      #pragma unroll
      for (int r = 0; r < 4; ++r) {
        int t_loc = tl + r;
        int tg = tbase + wave*16 + t_loc;
        float pv = 0.f;
        if (sg <= tg) {
          int lev = 31 - __clz((unsigned)((tg+1) ^ sg));
          lev = lev > 10 ? 10 : lev;
          pv = accS[jt][r] * __expf(gct_r[r] - gcs_r[jt]) * lamS[wave*16 + t_loc][lev];
        }
        int bo = (t_loc << 7) + ((jt*16 + l15) << 1);
        bo ^= (t_loc & 7) << 4;
        *(ushort*)((char*)Pw + bo) = f2b(pv);
      }
    }
    #pragma unroll
    for (int ks = 0; ks < 2; ++ks) {
      int bo = (l15 << 7) + ((ks*32 + kh*8) << 1);
      bo ^= (l15 & 7) << 4;
      bf16x8 pa = *(bf16x8*)((char*)Pw + bo);
      const ushort* up = &Ut[(size_t)(bh*128 + l15)*1024 + sbase + ks*32 + kh*8];
      #pragma unroll
      for (int dt = 0; dt < 8; ++dt) {
        bf16x8 uf = *(const bf16x8*)(up + (size_t)dt*16*1024);
        accO[dt] = __builtin_amdgcn_mfma_f32_16x16x32_bf16(pa, uf, accO[dt], 0, 0, 0);
      }
    }
  }
  float* og = Og + (size_t)half*2097152;
  #pragma unroll
  for (int dt = 0; dt < 8; ++dt) {
    #pragma unroll
    for (int r = 0; r < 4; ++r) {
      int row = tbase + wave*16 + tl + r;
      og[(size_t)(b*1024 + row)*1024 + h*128 + dt*16 + l15] = accO[dt][r];
    }
  }
}

// -------- gated RMSNorm (sums two partial O buffers) -> bf16 --------
__global__ __launch_bounds__(64) void normgate(const float* __restrict__ O1,
    const float* __restrict__ O2, const float* __restrict__ G,
    const float* __restrict__ norm_w, ushort* __restrict__ Y)
{
  int row = blockIdx.x;
  int lane = threadIdx.x;
  size_t base = (size_t)(row >> 3)*1024 + (size_t)(row & 7)*128;
  float2 oa = *(const float2*)&O1[base + lane*2];
  float2 ob = *(const float2*)&O2[base + lane*2];
  float ox = oa.x + ob.x, oy = oa.y + ob.y;
  float ss = ox*ox + oy*oy;
  #pragma unroll
  for (int m = 1; m < 64; m <<= 1) ss += __shfl_xor(ss, m);
  float r = rsqrtf(ss * (1.f/128.f) + 1e-5f);
  float2 g = *(const float2*)&G[base + lane*2];
  ushort2 y;
  y.x = f2b(ox * r * norm_w[lane*2+0] * (g.x * sigm(g.x)));
  y.y = f2b(oy * r * norm_w[lane*2+1] * (g.y * sigm(g.y)));
  *(ushort2*)&Y[base + lane*2] = y;
}

extern "C" void kernel_launch(void* const* d_in, const int* in_sizes, int n_in,
                              void* d_out, int out_size, void* d_ws, size_t ws_size,
                              hipStream_t stream)
{
  const float* x    = (const float*)d_in[0];
  const float* Wq   = (const float*)d_in[3];
  const float* Wk   = (const float*)d_in[4];
  const float* Wv   = (const float*)d_in[5];
  const float* Wb   = (const float*)d_in[6];
  const float* Wa   = (const float*)d_in[7];
  const float* Wl   = (const float*)d_in[8];
  const float* Wg   = (const float*)d_in[9];
  const float* Wo   = (const float*)d_in[10];
  const float* cq   = (const float*)d_in[11];
  const float* ck   = (const float*)d_in[12];
  const float* cv   = (const float*)d_in[13];
  const float* A_log   = (const float*)d_in[14];
  const float* dt_bias = (const float*)d_in[15];
  const float* norm_w  = (const float*)d_in[16];
  float* out = (float*)d_out;

  float* p = (float*)d_ws;
  float* xqkv = p;  p += 6291456;            // [2048][3072] f32 (dead after convs)
  float* xg   = p;  p += 2097152;
  float* kb   = p;  p += 2097152;
  float* vb   = p;  p += 2097152;
  float* o1   = p;  p += 2097152;            // o1,o2 MUST be adjacent (readout2 half offset)
  float* o2   = p;  p += 2097152;
  float* xs   = p;  p += 212992;
  float* gc   = p;  p += 16384;
  float* eD   = p;  p += 256;
  // NOTE: p is float*; every 2M-ushort (4MB) bf16 buffer needs p += 1048576 (R3 bug: 524288)
  ushort* x16 = (ushort*)p; p += 1048576;    // [2048][1024] bf16
  ushort* Wt4 = (ushort*)p; p += 2097152;    // [4096][1024] bf16
  ushort* Wot = (ushort*)p; p += 524288;     // [1024][1024] bf16
  float* Wsm  = p;  p += 106496;
  ushort* yb16= (ushort*)p; p += 1048576;    // [2048][1024] bf16
  ushort* qb16= (ushort*)p; p += 1048576;    // [2048][1024] bf16
  ushort* kb16= (ushort*)p; p += 1048576;    // [2048][1024] bf16
  ushort* ut16= (ushort*)p; p += 1048576;    // [16*128][1024] bf16
  float* cw  = xqkv;                          // overlay dead xqkv
  float* cWk = xqkv + 2097152;
  float* cKp = xqkv + 4194304;

  dim3 blk(256);
  cast_x<<<dim3(2048), blk, 0, stream>>>(x, x16);
  transcast<<<dim3(32,32), blk, 0, stream>>>(Wq, Wt4);
  transcast<<<dim3(32,32), blk, 0, stream>>>(Wk, Wt4 + 1024*1024);
  transcast<<<dim3(32,32), blk, 0, stream>>>(Wv, Wt4 + 2*1024*1024);
  transcast<<<dim3(32,32), blk, 0, stream>>>(Wg, Wt4 + 3*1024*1024);
  transcast<<<dim3(32,32), blk, 0, stream>>>(Wo, Wot);
  copy_wsmall<<<dim3(416), blk, 0, stream>>>(Wb, Wa, Wl, Wsm);
  gemm_bf16<<<dim3(32,16), blk, 0, stream>>>(x16, Wt4, xqkv, xg, 2048, 4096, 1024,
                                             3072, 3072, 1024);
  gemm_f32<<<dim3(2,32), blk, 0, stream>>>(x, Wsm, xs, 2048, 104, 1024);
  conv_silu<<<dim3(2048), blk, 0, stream>>>(xqkv + 0,    cq, nullptr, qb16, 0, 3072);
  conv_silu<<<dim3(2048), blk, 0, stream>>>(xqkv + 1024, ck, kb, kb16, 1, 3072);
  conv_silu<<<dim3(2048), blk, 0, stream>>>(xqkv + 2048, cv, vb, nullptr, 2, 3072);
  gc2<<<dim3(16), blk, 0, stream>>>(xs, A_log, dt_bias, gc);
  chunk_prep<<<dim3(256), blk, 0, stream>>>(kb, vb, xs, gc, cw, cWk, cKp, eD);
  chunk_scan<<<dim3(64), blk, 0, stream>>>(cw, cWk, cKp, eD, ut16);
  readout2<<<dim3(256,2), blk, 0, stream>>>(qb16, kb16, ut16, gc, xs, o1);
  normgate<<<dim3(16384), dim3(64), 0, stream>>>(o1, o2, xg, norm_w, yb16);
  gemm_bf16<<<dim3(8,16), blk, 0, stream>>>(yb16, Wot, out, out, 2048, 1024, 1024,
                                            1024, 1024, 1024);
}

// Round 5
// 349.748 us; speedup vs baseline: 7.0210x; 1.1259x over previous
//
#include <hip/hip_runtime.h>
#include <hip/hip_bf16.h>
#include <math.h>

// B=2, T=1024, D=1024, H=8, Dh=128, L=11, conv=4; chunk C=64, 16 chunks/bh
#define SCALE_Q 0.08838834764831845f

typedef __bf16 bf16x8 __attribute__((ext_vector_type(8)));
typedef float f32x4 __attribute__((ext_vector_type(4)));

static __device__ __forceinline__ float sigm(float x){ return 1.f/(1.f+__expf(-x)); }
static __device__ __forceinline__ ushort f2b(float v){
  __hip_bfloat16 t = __float2bfloat16(v);
  return __builtin_bit_cast(ushort, t);
}

// ---------------- cast x f32 -> bf16 ----------------
__global__ __launch_bounds__(256) void cast_x(const float* __restrict__ X,
    ushort* __restrict__ Y)
{
  int idx = blockIdx.x*256 + threadIdx.x;
  float4 v = *(const float4*)&X[(size_t)idx*4];
  ushort4 o; o.x=f2b(v.x); o.y=f2b(v.y); o.z=f2b(v.z); o.w=f2b(v.w);
  *(ushort4*)&Y[(size_t)idx*4] = o;
}

// ---------------- transpose + cast: Wt[n][k] = bf16(W[k][n]), 1024x1024 ----------------
__global__ __launch_bounds__(256) void transcast(const float* __restrict__ W,
    ushort* __restrict__ Wt)
{
  __shared__ float tile[32][36];
  int n0 = blockIdx.x*32, k0 = blockIdx.y*32;
  int tid = threadIdx.x;
  int r = tid >> 3, c4 = (tid & 7) << 2;
  *(float4*)&tile[r][c4] = *(const float4*)&W[(size_t)(k0 + r)*1024 + n0 + c4];
  __syncthreads();
  ushort4 o;
  o.x = f2b(tile[c4+0][r]); o.y = f2b(tile[c4+1][r]);
  o.z = f2b(tile[c4+2][r]); o.w = f2b(tile[c4+3][r]);
  *(ushort4*)&Wt[(size_t)(n0 + r)*1024 + k0 + c4] = o;
}

// ---------------- concat small weights: Wsm[k][0:8]=Wb, [8:16]=Wa, [16:104]=Wl ----------------
__global__ __launch_bounds__(256) void copy_wsmall(const float* __restrict__ Wb,
    const float* __restrict__ Wa, const float* __restrict__ Wl, float* __restrict__ Wsm)
{
  int idx = blockIdx.x*256 + threadIdx.x;
  if (idx >= 1024*104) return;
  int k = idx / 104, c = idx % 104;
  float v = (c < 8) ? Wb[k*8+c] : (c < 16) ? Wa[k*8+(c-8)] : Wl[k*88+(c-16)];
  Wsm[idx] = v;
}

// ---------------- bf16 MFMA GEMM: C[M,N] = A[M,K] @ Bt[N,K]^T, C f32, split cols ----------------
__global__ __launch_bounds__(256) void gemm_bf16(const ushort* __restrict__ A,
    const ushort* __restrict__ Bt, float* __restrict__ C0, float* __restrict__ C1,
    int M, int N, int K, int nsplit, int ld0, int ld1)
{
  __shared__ ushort As[128*32];
  __shared__ ushort Bs[128*32];
  int tid = threadIdx.x;
  int bm = blockIdx.y * 128, bn = blockIdx.x * 128;
  int wave = tid >> 6, lane = tid & 63;
  int wm = (wave >> 1) * 64, wn = (wave & 1) * 64;
  int l16 = lane & 15, kh = lane >> 4;
  f32x4 acc[4][4] = {};
  int rowA0 = tid >> 2, boA = (tid & 3) * 16;
  for (int k0 = 0; k0 < K; k0 += 32) {
    #pragma unroll
    for (int j = 0; j < 2; ++j) {
      int row = rowA0 + j*64;
      const char* gA = (const char*)A + (((size_t)(bm+row)*K + k0)*2 + boA);
      const char* gB = (const char*)Bt + (((size_t)(bn+row)*K + k0)*2 + boA);
      __builtin_amdgcn_global_load_lds((const __attribute__((address_space(1))) unsigned*)gA,
        (__attribute__((address_space(3))) unsigned*)((char*)As + row*64 + boA), 16, 0, 0);
      __builtin_amdgcn_global_load_lds((const __attribute__((address_space(1))) unsigned*)gB,
        (__attribute__((address_space(3))) unsigned*)((char*)Bs + row*64 + boA), 16, 0, 0);
    }
    __syncthreads();
    bf16x8 af[4], bfr[4];
    #pragma unroll
    for (int i = 0; i < 4; ++i)
      af[i] = *(bf16x8*)((char*)As + (wm + i*16 + l16)*64 + kh*16);
    #pragma unroll
    for (int j = 0; j < 4; ++j)
      bfr[j] = *(bf16x8*)((char*)Bs + (wn + j*16 + l16)*64 + kh*16);
    #pragma unroll
    for (int i = 0; i < 4; ++i)
      #pragma unroll
      for (int j = 0; j < 4; ++j)
        acc[i][j] = __builtin_amdgcn_mfma_f32_16x16x32_bf16(af[i], bfr[j], acc[i][j], 0, 0, 0);
    __syncthreads();
  }
  int rg = lane >> 4;
  #pragma unroll
  for (int i = 0; i < 4; ++i) {
    #pragma unroll
    for (int j = 0; j < 4; ++j) {
      int col = bn + wn + j*16 + l16;
      #pragma unroll
      for (int r = 0; r < 4; ++r) {
        int row = bm + wm + i*16 + rg*4 + r;
        float v = acc[i][j][r];
        if (col < nsplit) C0[(size_t)row*ld0 + col] = v;
        else              C1[(size_t)row*ld1 + (col - nsplit)] = v;
      }
    }
  }
}

// ---------------- f32 tiled GEMM (small N=104 projection) ----------------
__global__ __launch_bounds__(256) void gemm_f32(const float* __restrict__ A,
    const float* __restrict__ B, float* __restrict__ C, int M, int N, int K)
{
  __shared__ float As[16][64];
  __shared__ float Bs[16][64];
  int tid = threadIdx.x;
  int bm = blockIdx.y * 64, bn = blockIdx.x * 64;
  int tx = tid & 15, ty = tid >> 4;
  int am = tid >> 2, ak = (tid & 3) << 2;
  int bk = tid >> 4, bn4 = (tid & 15) << 2;
  float acc[4][4] = {};
  for (int k0 = 0; k0 < K; k0 += 16) {
    float4 a4 = *(const float4*)&A[(size_t)(bm+am)*K + k0 + ak];
    As[ak+0][am] = a4.x; As[ak+1][am] = a4.y; As[ak+2][am] = a4.z; As[ak+3][am] = a4.w;
    float4 b4;
    int col = bn + bn4;
    if (col + 3 < N) {
      b4 = *(const float4*)&B[(size_t)(k0+bk)*N + col];
    } else {
      const float* bp = &B[(size_t)(k0+bk)*N];
      b4.x = (col+0<N)? bp[col+0]:0.f; b4.y = (col+1<N)? bp[col+1]:0.f;
      b4.z = (col+2<N)? bp[col+2]:0.f; b4.w = (col+3<N)? bp[col+3]:0.f;
    }
    *(float4*)&Bs[bk][bn4] = b4;
    __syncthreads();
    #pragma unroll
    for (int kk = 0; kk < 16; ++kk) {
      float4 av = *(const float4*)&As[kk][ty<<2];
      float4 bv = *(const float4*)&Bs[kk][tx<<2];
      float a_[4] = {av.x,av.y,av.z,av.w};
      float b_[4] = {bv.x,bv.y,bv.z,bv.w};
      #pragma unroll
      for (int i2 = 0; i2 < 4; ++i2)
        #pragma unroll
        for (int j2 = 0; j2 < 4; ++j2)
          acc[i2][j2] += a_[i2]*b_[j2];
    }
    __syncthreads();
  }
  #pragma unroll
  for (int i2 = 0; i2 < 4; ++i2) {
    int row = bm + (ty<<2) + i2;
    #pragma unroll
    for (int j2 = 0; j2 < 4; ++j2) {
      int col = bn + (tx<<2) + j2;
      if (col < N) C[(size_t)row*N + col] = acc[i2][j2];
    }
  }
}

// -------- depthwise causal conv(4) + silu (+ optional l2norm); f32 and/or bf16 out --------
__global__ __launch_bounds__(256) void conv_silu(const float* __restrict__ X,
    const float* __restrict__ W, float* __restrict__ Yf, ushort* __restrict__ Yb,
    int mode, int ldx)
{
  int row = blockIdx.x;
  int b = row >> 10, t = row & 1023;
  int tid = threadIdx.x;
  int c0 = tid << 2;
  float w[4][4];
  #pragma unroll
  for (int c = 0; c < 4; ++c) {
    float4 wv = *(const float4*)&W[(c0 + c)*4];
    w[c][0]=wv.x; w[c][1]=wv.y; w[c][2]=wv.z; w[c][3]=wv.w;
  }
  float acc[4] = {0.f,0.f,0.f,0.f};
  #pragma unroll
  for (int j = 0; j < 4; ++j) {
    int tt = t - 3 + j;
    if (tt >= 0) {
      float4 xv = *(const float4*)&X[(size_t)(b*1024 + tt)*ldx + c0];
      acc[0] += w[0][j]*xv.x; acc[1] += w[1][j]*xv.y;
      acc[2] += w[2][j]*xv.z; acc[3] += w[3][j]*xv.w;
    }
  }
  #pragma unroll
  for (int c = 0; c < 4; ++c) acc[c] *= sigm(acc[c]);
  if (mode < 2) {
    float ss = acc[0]*acc[0]+acc[1]*acc[1]+acc[2]*acc[2]+acc[3]*acc[3];
    ss += __shfl_xor(ss, 1); ss += __shfl_xor(ss, 2); ss += __shfl_xor(ss, 4);
    ss += __shfl_xor(ss, 8); ss += __shfl_xor(ss, 16);
    float r = rsqrtf(ss + 1e-6f);
    if (mode == 0) r *= SCALE_Q;
    acc[0]*=r; acc[1]*=r; acc[2]*=r; acc[3]*=r;
  }
  size_t o = (size_t)(b*1024 + t)*1024 + c0;
  if (mode != 0) {
    float4 yv; yv.x=acc[0]; yv.y=acc[1]; yv.z=acc[2]; yv.w=acc[3];
    *(float4*)&Yf[o] = yv;
  }
  if (mode != 2) {
    ushort4 yb; yb.x=f2b(acc[0]); yb.y=f2b(acc[1]); yb.z=f2b(acc[2]); yb.w=f2b(acc[3]);
    *(ushort4*)&Yb[o] = yb;
  }
}

// -------- per-(b,h) log-decay cumsum, one block per bh --------
__global__ __launch_bounds__(256) void gc2(const float* __restrict__ xs,
    const float* __restrict__ A_log, const float* __restrict__ dt_bias,
    float* __restrict__ gc)
{
  int bh = blockIdx.x, b = bh >> 3, h = bh & 7;
  __shared__ float sc[256];
  int tid = threadIdx.x;
  float aexp = __expf(A_log[h]), db = dt_bias[h];
  int t0 = tid*4;
  float g[4], csum = 0.f;
  #pragma unroll
  for (int z = 0; z < 4; ++z) {
    float zv = xs[(size_t)(b*1024 + t0 + z)*104 + 8 + h] + db;
    float sp = (zv > 20.f) ? zv : log1pf(__expf(zv));
    csum += -aexp*sp;
    g[z] = csum;
  }
  sc[tid] = csum;
  __syncthreads();
  for (int ofs = 1; ofs < 256; ofs <<= 1) {
    float v = (tid >= ofs) ? sc[tid-ofs] : 0.f;
    __syncthreads();
    sc[tid] += v;
    __syncthreads();
  }
  float excl = sc[tid] - csum;
  #pragma unroll
  for (int z = 0; z < 4; ++z) gc[bh*1024 + t0 + z] = excl + g[z];
}

// -------- chunk prep: per (bh,chunk of 64): A, in-register fwd substitution --------
__global__ __launch_bounds__(256) void chunk_prep(const float* __restrict__ Kg,
    const float* __restrict__ Vg, const float* __restrict__ xs,
    const float* __restrict__ gcg, float* __restrict__ cw, float* __restrict__ cWk,
    float* __restrict__ cKp, float* __restrict__ eD)
{
  int blk = blockIdx.x;
  int bh = blk >> 4, ck = blk & 15;
  int b = bh >> 3, h = bh & 7;
  int a = ck << 6;
  __shared__ float Kc[64][132];
  __shared__ float As[64][68];
  __shared__ float gcl[65];
  __shared__ float bl[64];
  __shared__ float egc[64];
  __shared__ float edt[64];
  int tid = threadIdx.x;
  for (int e = tid; e < 64*32; e += 256) {
    int t = e >> 5, c4 = (e & 31) << 2;
    *(float4*)&Kc[t][c4] = *(const float4*)&Kg[(size_t)(b*1024 + a + t)*1024 + h*128 + c4];
  }
  if (tid < 64) {
    gcl[tid] = gcg[bh*1024 + a + tid];
    bl[tid] = sigm(xs[(size_t)(b*1024 + a + tid)*104 + h]);
  }
  if (tid == 64) gcl[64] = (ck < 15) ? gcg[bh*1024 + a + 64] : 0.f;
  __syncthreads();
  if (tid < 64) {
    egc[tid] = __expf(gcl[tid] - gcl[0]);
    edt[tid] = (ck < 15) ? __expf(gcl[64] - gcl[tid]) : 0.f;
  }
  {
    int ti = tid >> 4, si = tid & 15;
    if (si <= ti) {
      float dot[4][4] = {};
      for (int kk = 0; kk < 128; kk += 4) {
        float4 kt[4], ks[4];
        #pragma unroll
        for (int z = 0; z < 4; ++z) kt[z] = *(float4*)&Kc[ti*4+z][kk];
        #pragma unroll
        for (int z = 0; z < 4; ++z) ks[z] = *(float4*)&Kc[si*4+z][kk];
        #pragma unroll
        for (int i = 0; i < 4; ++i)
          #pragma unroll
          for (int j = 0; j < 4; ++j)
            dot[i][j] += kt[i].x*ks[j].x + kt[i].y*ks[j].y + kt[i].z*ks[j].z + kt[i].w*ks[j].w;
      }
      #pragma unroll
      for (int i = 0; i < 4; ++i) {
        int t = ti*4 + i;
        #pragma unroll
        for (int j = 0; j < 4; ++j) {
          int s = si*4 + j;
          if (s < t) As[t][s] = bl[t]*dot[i][j]*__expf(gcl[t]-gcl[s]);
        }
      }
    }
  }
  __syncthreads();
  int c = tid;
  float u[64];
  if (c < 128) {
    #pragma unroll
    for (int t = 0; t < 64; ++t)
      u[t] = bl[t]*Vg[(size_t)(b*1024 + a + t)*1024 + h*128 + c];
  } else {
    int d = c - 128;
    #pragma unroll
    for (int t = 0; t < 64; ++t)
      u[t] = bl[t]*egc[t]*Kc[t][d];
  }
  #pragma unroll
  for (int t = 1; t < 64; ++t) {
    float acc = u[t];
    int s = 0;
    #pragma unroll
    for (; s + 4 <= t; s += 4) {
      float4 a4 = *(float4*)&As[t][s];
      acc -= a4.x*u[s] + a4.y*u[s+1] + a4.z*u[s+2] + a4.w*u[s+3];
    }
    #pragma unroll
    for (; s < t; ++s) acc -= As[t][s]*u[s];
    u[t] = acc;
  }
  size_t cbase = (size_t)blk*8192;
  if (c < 128) {
    #pragma unroll
    for (int t = 0; t < 64; ++t)
      cw[cbase + t*128 + c] = u[t];
  } else {
    int d = c - 128;
    #pragma unroll
    for (int t = 0; t < 64; ++t) {
      cWk[cbase + t*128 + d] = u[t];
      cKp[cbase + t*128 + d] = Kc[t][d]*edt[t];
    }
  }
  if (tid == 0) eD[blk] = (ck < 15) ? __expf(gcl[64]-gcl[0]) : 0.f;
}

// -------- chunk scan v2: 256 blocks = 16 dv-slices(8 cols) x 16 bh --------
// Double-buffered global_load_lds staging (XOR-swizzled via pre-swizzled source),
// S kept transposed St[e][k] in LDS, w register-prefetched one step ahead.
// blk = slice*16+bh so all slices of a bh share an XCD's L2 for Wk/Kp.
__global__ __launch_bounds__(256) void chunk_scan2(const float* __restrict__ cw,
    const float* __restrict__ cWk, const float* __restrict__ cKp,
    const float* __restrict__ eD, ushort* __restrict__ Ut)
{
  int blk = blockIdx.x;
  int slice = blk >> 4, bh = blk & 15;
  int e_base = slice << 3;
  __shared__ float Wks[2][8192];   // [64][128] f32 per buffer, swizzled cols
  __shared__ float Kps[2][8192];
  __shared__ float St[8][132];     // S transposed [e][k]
  __shared__ float us[64][9];
  int tid = threadIdx.x;
  float* stf = &St[0][0];
  for (int idx = tid; idx < 8*132; idx += 256) stf[idx] = 0.f;

  int tu = tid >> 2, e0 = (tid & 3) << 1;   // u-phase: (t, e-pair)
  int swu = tu & 7;
  int es = tid >> 5, k4 = tid & 31;         // S-phase: (e, k-quad)

  // prefetch w for step 0; stage chunk 0 into buf 0
  int ci0 = bh << 4;
  float2 wv = *(const float2*)&cw[(size_t)ci0*8192 + tu*128 + e_base + e0];
  {
    const char* wg = (const char*)(cWk + (size_t)ci0*8192);
    const char* kg = (const char*)(cKp + (size_t)ci0*8192);
    #pragma unroll
    for (int j = 0; j < 8; ++j) {
      unsigned off = (j<<12) + (tid<<4);
      unsigned so = off ^ ((((off>>9)&7u))<<4);
      __builtin_amdgcn_global_load_lds((const __attribute__((address_space(1))) unsigned*)(wg + so),
        (__attribute__((address_space(3))) unsigned*)((char*)&Wks[0][0] + off), 16, 0, 0);
      __builtin_amdgcn_global_load_lds((const __attribute__((address_space(1))) unsigned*)(kg + so),
        (__attribute__((address_space(3))) unsigned*)((char*)&Kps[0][0] + off), 16, 0, 0);
    }
  }
  __syncthreads();

  for (int i = 0; i < 16; ++i) {
    int ci = ci0 + i, a = i << 6, cur = i & 1;
    float2 wv_next;
    if (i < 15) {
      // issue next w prefetch FIRST so its wait doesn't queue behind staging
      wv_next = *(const float2*)&cw[(size_t)(ci+1)*8192 + tu*128 + e_base + e0];
      const char* wg = (const char*)(cWk + (size_t)(ci+1)*8192);
      const char* kg = (const char*)(cKp + (size_t)(ci+1)*8192);
      char* wl = (char*)&Wks[cur^1][0];
      char* kl = (char*)&Kps[cur^1][0];
      #pragma unroll
      for (int j = 0; j < 8; ++j) {
        unsigned off = (j<<12) + (tid<<4);
        unsigned so = off ^ ((((off>>9)&7u))<<4);
        __builtin_amdgcn_global_load_lds((const __attribute__((address_space(1))) unsigned*)(wg + so),
          (__attribute__((address_space(3))) unsigned*)(wl + off), 16, 0, 0);
        __builtin_amdgcn_global_load_lds((const __attribute__((address_space(1))) unsigned*)(kg + so),
          (__attribute__((address_space(3))) unsigned*)(kl + off), 16, 0, 0);
      }
    }
    // u-phase: u[t][e] = w - sum_k Wk[t][k] * St[e][k]
    {
      float acc0 = wv.x, acc1 = wv.y;
      const char* wb = (const char*)&Wks[cur][0];
      const f32x4* s0p = (const f32x4*)&St[e0][0];
      const f32x4* s1p = (const f32x4*)&St[e0+1][0];
      #pragma unroll 8
      for (int k = 0; k < 32; ++k) {
        f32x4 wk = *(const f32x4*)(wb + (tu<<9) + ((k ^ swu)<<4));
        f32x4 s0 = s0p[k];
        f32x4 s1 = s1p[k];
        acc0 -= wk[0]*s0[0] + wk[1]*s0[1] + wk[2]*s0[2] + wk[3]*s0[3];
        acc1 -= wk[0]*s1[0] + wk[1]*s1[1] + wk[2]*s1[2] + wk[3]*s1[3];
      }
      us[tu][e0]   = acc0;
      us[tu][e0+1] = acc1;
      size_t ur = (size_t)(bh*128 + e_base + e0)*1024 + a + tu;
      Ut[ur]        = f2b(acc0);
      Ut[ur + 1024] = f2b(acc1);
    }
    __syncthreads();
    // S-phase: St[e][k] = eD*St[e][k] + sum_t Kp[t][k]*u[t][e]
    if (i < 15) {
      float ed = eD[ci];
      f32x4 sa = ed * *(f32x4*)&St[es][k4<<2];
      const char* kb = (const char*)&Kps[cur][0];
      #pragma unroll 8
      for (int t = 0; t < 64; ++t) {
        f32x4 kp = *(const f32x4*)(kb + (t<<9) + ((k4 ^ (t&7))<<4));
        float uv = us[t][es];
        sa += kp * uv;
      }
      *(f32x4*)&St[es][k4<<2] = sa;
      wv = wv_next;
    }
    __syncthreads();
  }
}

// -------- MFMA log-linear readout --------
// grid (x: 16bh x 16 qchunks of 64, y: 2 s-halves). 4 waves x 16 q-rows.
__global__ __launch_bounds__(256) void readout2(const ushort* __restrict__ Qb,
    const ushort* __restrict__ Kb, const ushort* __restrict__ Ut,
    const float* __restrict__ gcg, const float* __restrict__ xs,
    float* __restrict__ Og)
{
  int blk = blockIdx.x;
  int bh = blk >> 4, ic = blk & 15;
  int half = blockIdx.y;
  int b = bh >> 3, h = bh & 7;
  int tbase = ic << 6;
  __shared__ ushort Pl[4][1024];       // 16x64 bf16 per wave, XOR-swizzled
  __shared__ float lamS[64][12];
  int tid = threadIdx.x;
  int wave = tid >> 6, lane = tid & 63;
  int l15 = lane & 15, kh = lane >> 4;
  for (int e = tid; e < 64*11; e += 256) {
    int t = e/11, l = e%11;
    lamS[t][l] = sigm(xs[(size_t)(b*1024+tbase+t)*104 + 16 + h*11 + l]);
  }
  int tl = kh*4;
  float gct_r[4];
  #pragma unroll
  for (int r = 0; r < 4; ++r) gct_r[r] = gcg[bh*1024 + tbase + wave*16 + tl + r];
  bf16x8 qf[4];
  {
    const ushort* qp = &Qb[(size_t)(b*1024 + tbase + wave*16 + l15)*1024 + h*128 + kh*8];
    #pragma unroll
    for (int kk = 0; kk < 4; ++kk) qf[kk] = *(const bf16x8*)(qp + kk*32);
  }
  __syncthreads();                     // lamS ready
  f32x4 accO[8] = {};
  int nsteps = ic + 1;
  int jmid = (nsteps + 1) >> 1;
  int j0 = half ? jmid : 0;
  int j1 = half ? nsteps : jmid;
  ushort* Pw = &Pl[wave][0];
  for (int j = j0; j < j1; ++j) {
    int sbase = j << 6;
    float gcs_r[4];
    #pragma unroll
    for (int jt = 0; jt < 4; ++jt)
      gcs_r[jt] = gcg[bh*1024 + sbase + jt*16 + l15];
    f32x4 accS[4] = {};
    #pragma unroll
    for (int jt = 0; jt < 4; ++jt) {
      const ushort* kp = &Kb[(size_t)(b*1024 + sbase + jt*16 + l15)*1024 + h*128 + kh*8];
      #pragma unroll
      for (int kk = 0; kk < 4; ++kk) {
        bf16x8 kf = *(const bf16x8*)(kp + kk*32);
        accS[jt] = __builtin_amdgcn_mfma_f32_16x16x32_bf16(qf[kk], kf, accS[jt], 0, 0, 0);
      }
    }
    #pragma unroll
    for (int jt = 0; jt < 4; ++jt) {
      int sg = sbase + jt*16 + l15;
      #pragma unroll
      for (int r = 0; r < 4; ++r) {
        int t_loc = tl + r;
        int tg = tbase + wave*16 + t_loc;
        float pv = 0.f;
        if (sg <= tg) {
          int lev = 31 - __clz((unsigned)((tg+1) ^ sg));
          lev = lev > 10 ? 10 : lev;
          pv = accS[jt][r] * __expf(gct_r[r] - gcs_r[jt]) * lamS[wave*16 + t_loc][lev];
        }
        int bo = (t_loc << 7) + ((jt*16 + l15) << 1);
        bo ^= (t_loc & 7) << 4;
        *(ushort*)((char*)Pw + bo) = f2b(pv);
      }
    }
    #pragma unroll
    for (int ks = 0; ks < 2; ++ks) {
      int bo = (l15 << 7) + ((ks*32 + kh*8) << 1);
      bo ^= (l15 & 7) << 4;
      bf16x8 pa = *(bf16x8*)((char*)Pw + bo);
      const ushort* up = &Ut[(size_t)(bh*128 + l15)*1024 + sbase + ks*32 + kh*8];
      #pragma unroll
      for (int dt = 0; dt < 8; ++dt) {
        bf16x8 uf = *(const bf16x8*)(up + (size_t)dt*16*1024);
        accO[dt] = __builtin_amdgcn_mfma_f32_16x16x32_bf16(pa, uf, accO[dt], 0, 0, 0);
      }
    }
  }
  float* og = Og + (size_t)half*2097152;
  #pragma unroll
  for (int dt = 0; dt < 8; ++dt) {
    #pragma unroll
    for (int r = 0; r < 4; ++r) {
      int row = tbase + wave*16 + tl + r;
      og[(size_t)(b*1024 + row)*1024 + h*128 + dt*16 + l15] = accO[dt][r];
    }
  }
}

// -------- gated RMSNorm (sums two partial O buffers) -> bf16 --------
__global__ __launch_bounds__(64) void normgate(const float* __restrict__ O1,
    const float* __restrict__ O2, const float* __restrict__ G,
    const float* __restrict__ norm_w, ushort* __restrict__ Y)
{
  int row = blockIdx.x;
  int lane = threadIdx.x;
  size_t base = (size_t)(row >> 3)*1024 + (size_t)(row & 7)*128;
  float2 oa = *(const float2*)&O1[base + lane*2];
  float2 ob = *(const float2*)&O2[base + lane*2];
  float ox = oa.x + ob.x, oy = oa.y + ob.y;
  float ss = ox*ox + oy*oy;
  #pragma unroll
  for (int m = 1; m < 64; m <<= 1) ss += __shfl_xor(ss, m);
  float r = rsqrtf(ss * (1.f/128.f) + 1e-5f);
  float2 g = *(const float2*)&G[base + lane*2];
  ushort2 y;
  y.x = f2b(ox * r * norm_w[lane*2+0] * (g.x * sigm(g.x)));
  y.y = f2b(oy * r * norm_w[lane*2+1] * (g.y * sigm(g.y)));
  *(ushort2*)&Y[base + lane*2] = y;
}

extern "C" void kernel_launch(void* const* d_in, const int* in_sizes, int n_in,
                              void* d_out, int out_size, void* d_ws, size_t ws_size,
                              hipStream_t stream)
{
  const float* x    = (const float*)d_in[0];
  const float* Wq   = (const float*)d_in[3];
  const float* Wk   = (const float*)d_in[4];
  const float* Wv   = (const float*)d_in[5];
  const float* Wb   = (const float*)d_in[6];
  const float* Wa   = (const float*)d_in[7];
  const float* Wl   = (const float*)d_in[8];
  const float* Wg   = (const float*)d_in[9];
  const float* Wo   = (const float*)d_in[10];
  const float* cq   = (const float*)d_in[11];
  const float* ck   = (const float*)d_in[12];
  const float* cv   = (const float*)d_in[13];
  const float* A_log   = (const float*)d_in[14];
  const float* dt_bias = (const float*)d_in[15];
  const float* norm_w  = (const float*)d_in[16];
  float* out = (float*)d_out;

  float* p = (float*)d_ws;
  float* xqkv = p;  p += 6291456;            // [2048][3072] f32 (dead after convs)
  float* xg   = p;  p += 2097152;
  float* kb   = p;  p += 2097152;
  float* vb   = p;  p += 2097152;
  float* o1   = p;  p += 2097152;            // o1,o2 MUST be adjacent (readout2 half offset)
  float* o2   = p;  p += 2097152;
  float* xs   = p;  p += 212992;
  float* gc   = p;  p += 16384;
  float* eD   = p;  p += 256;
  // NOTE: p is float*; every 2M-ushort (4MB) bf16 buffer needs p += 1048576
  ushort* x16 = (ushort*)p; p += 1048576;    // [2048][1024] bf16
  ushort* Wt4 = (ushort*)p; p += 2097152;    // [4096][1024] bf16
  ushort* Wot = (ushort*)p; p += 524288;     // [1024][1024] bf16
  float* Wsm  = p;  p += 106496;
  ushort* yb16= (ushort*)p; p += 1048576;    // [2048][1024] bf16
  ushort* qb16= (ushort*)p; p += 1048576;    // [2048][1024] bf16
  ushort* kb16= (ushort*)p; p += 1048576;    // [2048][1024] bf16
  ushort* ut16= (ushort*)p; p += 1048576;    // [16*128][1024] bf16
  float* cw  = xqkv;                          // overlay dead xqkv
  float* cWk = xqkv + 2097152;
  float* cKp = xqkv + 4194304;

  dim3 blk(256);
  cast_x<<<dim3(2048), blk, 0, stream>>>(x, x16);
  transcast<<<dim3(32,32), blk, 0, stream>>>(Wq, Wt4);
  transcast<<<dim3(32,32), blk, 0, stream>>>(Wk, Wt4 + 1024*1024);
  transcast<<<dim3(32,32), blk, 0, stream>>>(Wv, Wt4 + 2*1024*1024);
  transcast<<<dim3(32,32), blk, 0, stream>>>(Wg, Wt4 + 3*1024*1024);
  transcast<<<dim3(32,32), blk, 0, stream>>>(Wo, Wot);
  copy_wsmall<<<dim3(416), blk, 0, stream>>>(Wb, Wa, Wl, Wsm);
  gemm_bf16<<<dim3(32,16), blk, 0, stream>>>(x16, Wt4, xqkv, xg, 2048, 4096, 1024,
                                             3072, 3072, 1024);
  gemm_f32<<<dim3(2,32), blk, 0, stream>>>(x, Wsm, xs, 2048, 104, 1024);
  conv_silu<<<dim3(2048), blk, 0, stream>>>(xqkv + 0,    cq, nullptr, qb16, 0, 3072);
  conv_silu<<<dim3(2048), blk, 0, stream>>>(xqkv + 1024, ck, kb, kb16, 1, 3072);
  conv_silu<<<dim3(2048), blk, 0, stream>>>(xqkv + 2048, cv, vb, nullptr, 2, 3072);
  gc2<<<dim3(16), blk, 0, stream>>>(xs, A_log, dt_bias, gc);
  chunk_prep<<<dim3(256), blk, 0, stream>>>(kb, vb, xs, gc, cw, cWk, cKp, eD);
  chunk_scan2<<<dim3(256), blk, 0, stream>>>(cw, cWk, cKp, eD, ut16);
  readout2<<<dim3(256,2), blk, 0, stream>>>(qb16, kb16, ut16, gc, xs, o1);
  normgate<<<dim3(16384), dim3(64), 0, stream>>>(o1, o2, xg, norm_w, yb16);
  gemm_bf16<<<dim3(8,16), blk, 0, stream>>>(yb16, Wot, out, out, 2048, 1024, 1024,
                                            1024, 1024, 1024);
}

// Round 6
// 305.051 us; speedup vs baseline: 8.0497x; 1.1465x over previous
//
#include <hip/hip_runtime.h>
#include <hip/hip_bf16.h>
#include <math.h>

// B=2, T=1024, D=1024, H=8, Dh=128, L=11, conv=4; chunk C=64, 16 chunks/bh
#define SCALE_Q 0.08838834764831845f

typedef __bf16 bf16x8 __attribute__((ext_vector_type(8)));
typedef float f32x4 __attribute__((ext_vector_type(4)));

static __device__ __forceinline__ float sigm(float x){ return 1.f/(1.f+__expf(-x)); }
static __device__ __forceinline__ ushort f2b(float v){
  __hip_bfloat16 t = __float2bfloat16(v);
  return __builtin_bit_cast(ushort, t);
}

// ---------------- cast x f32 -> bf16 ----------------
__global__ __launch_bounds__(256) void cast_x(const float* __restrict__ X,
    ushort* __restrict__ Y)
{
  int idx = blockIdx.x*256 + threadIdx.x;
  float4 v = *(const float4*)&X[(size_t)idx*4];
  ushort4 o; o.x=f2b(v.x); o.y=f2b(v.y); o.z=f2b(v.z); o.w=f2b(v.w);
  *(ushort4*)&Y[(size_t)idx*4] = o;
}

// ---------------- transpose + cast: Wt[n][k] = bf16(W[k][n]), 1024x1024 ----------------
__global__ __launch_bounds__(256) void transcast(const float* __restrict__ W,
    ushort* __restrict__ Wt)
{
  __shared__ float tile[32][36];
  int n0 = blockIdx.x*32, k0 = blockIdx.y*32;
  int tid = threadIdx.x;
  int r = tid >> 3, c4 = (tid & 7) << 2;
  *(float4*)&tile[r][c4] = *(const float4*)&W[(size_t)(k0 + r)*1024 + n0 + c4];
  __syncthreads();
  ushort4 o;
  o.x = f2b(tile[c4+0][r]); o.y = f2b(tile[c4+1][r]);
  o.z = f2b(tile[c4+2][r]); o.w = f2b(tile[c4+3][r]);
  *(ushort4*)&Wt[(size_t)(n0 + r)*1024 + k0 + c4] = o;
}

// ---------------- concat small weights: Wsm[k][0:8]=Wb, [8:16]=Wa, [16:104]=Wl ----------------
__global__ __launch_bounds__(256) void copy_wsmall(const float* __restrict__ Wb,
    const float* __restrict__ Wa, const float* __restrict__ Wl, float* __restrict__ Wsm)
{
  int idx = blockIdx.x*256 + threadIdx.x;
  if (idx >= 1024*104) return;
  int k = idx / 104, c = idx % 104;
  float v = (c < 8) ? Wb[k*8+c] : (c < 16) ? Wa[k*8+(c-8)] : Wl[k*88+(c-16)];
  Wsm[idx] = v;
}

// ---------------- bf16 MFMA GEMM: C[M,N] = A[M,K] @ Bt[N,K]^T, C f32, split cols ----------------
__global__ __launch_bounds__(256) void gemm_bf16(const ushort* __restrict__ A,
    const ushort* __restrict__ Bt, float* __restrict__ C0, float* __restrict__ C1,
    int M, int N, int K, int nsplit, int ld0, int ld1)
{
  __shared__ ushort As[128*32];
  __shared__ ushort Bs[128*32];
  int tid = threadIdx.x;
  int bm = blockIdx.y * 128, bn = blockIdx.x * 128;
  int wave = tid >> 6, lane = tid & 63;
  int wm = (wave >> 1) * 64, wn = (wave & 1) * 64;
  int l16 = lane & 15, kh = lane >> 4;
  f32x4 acc[4][4] = {};
  int rowA0 = tid >> 2, boA = (tid & 3) * 16;
  for (int k0 = 0; k0 < K; k0 += 32) {
    #pragma unroll
    for (int j = 0; j < 2; ++j) {
      int row = rowA0 + j*64;
      const char* gA = (const char*)A + (((size_t)(bm+row)*K + k0)*2 + boA);
      const char* gB = (const char*)Bt + (((size_t)(bn+row)*K + k0)*2 + boA);
      __builtin_amdgcn_global_load_lds((const __attribute__((address_space(1))) unsigned*)gA,
        (__attribute__((address_space(3))) unsigned*)((char*)As + row*64 + boA), 16, 0, 0);
      __builtin_amdgcn_global_load_lds((const __attribute__((address_space(1))) unsigned*)gB,
        (__attribute__((address_space(3))) unsigned*)((char*)Bs + row*64 + boA), 16, 0, 0);
    }
    __syncthreads();
    bf16x8 af[4], bfr[4];
    #pragma unroll
    for (int i = 0; i < 4; ++i)
      af[i] = *(bf16x8*)((char*)As + (wm + i*16 + l16)*64 + kh*16);
    #pragma unroll
    for (int j = 0; j < 4; ++j)
      bfr[j] = *(bf16x8*)((char*)Bs + (wn + j*16 + l16)*64 + kh*16);
    #pragma unroll
    for (int i = 0; i < 4; ++i)
      #pragma unroll
      for (int j = 0; j < 4; ++j)
        acc[i][j] = __builtin_amdgcn_mfma_f32_16x16x32_bf16(af[i], bfr[j], acc[i][j], 0, 0, 0);
    __syncthreads();
  }
  int rg = lane >> 4;
  #pragma unroll
  for (int i = 0; i < 4; ++i) {
    #pragma unroll
    for (int j = 0; j < 4; ++j) {
      int col = bn + wn + j*16 + l16;
      #pragma unroll
      for (int r = 0; r < 4; ++r) {
        int row = bm + wm + i*16 + rg*4 + r;
        float v = acc[i][j][r];
        if (col < nsplit) C0[(size_t)row*ld0 + col] = v;
        else              C1[(size_t)row*ld1 + (col - nsplit)] = v;
      }
    }
  }
}

// ---------------- f32 tiled GEMM (small N=104 projection) ----------------
__global__ __launch_bounds__(256) void gemm_f32(const float* __restrict__ A,
    const float* __restrict__ B, float* __restrict__ C, int M, int N, int K)
{
  __shared__ float As[16][64];
  __shared__ float Bs[16][64];
  int tid = threadIdx.x;
  int bm = blockIdx.y * 64, bn = blockIdx.x * 64;
  int tx = tid & 15, ty = tid >> 4;
  int am = tid >> 2, ak = (tid & 3) << 2;
  int bk = tid >> 4, bn4 = (tid & 15) << 2;
  float acc[4][4] = {};
  for (int k0 = 0; k0 < K; k0 += 16) {
    float4 a4 = *(const float4*)&A[(size_t)(bm+am)*K + k0 + ak];
    As[ak+0][am] = a4.x; As[ak+1][am] = a4.y; As[ak+2][am] = a4.z; As[ak+3][am] = a4.w;
    float4 b4;
    int col = bn + bn4;
    if (col + 3 < N) {
      b4 = *(const float4*)&B[(size_t)(k0+bk)*N + col];
    } else {
      const float* bp = &B[(size_t)(k0+bk)*N];
      b4.x = (col+0<N)? bp[col+0]:0.f; b4.y = (col+1<N)? bp[col+1]:0.f;
      b4.z = (col+2<N)? bp[col+2]:0.f; b4.w = (col+3<N)? bp[col+3]:0.f;
    }
    *(float4*)&Bs[bk][bn4] = b4;
    __syncthreads();
    #pragma unroll
    for (int kk = 0; kk < 16; ++kk) {
      float4 av = *(const float4*)&As[kk][ty<<2];
      float4 bv = *(const float4*)&Bs[kk][tx<<2];
      float a_[4] = {av.x,av.y,av.z,av.w};
      float b_[4] = {bv.x,bv.y,bv.z,bv.w};
      #pragma unroll
      for (int i2 = 0; i2 < 4; ++i2)
        #pragma unroll
        for (int j2 = 0; j2 < 4; ++j2)
          acc[i2][j2] += a_[i2]*b_[j2];
    }
    __syncthreads();
  }
  #pragma unroll
  for (int i2 = 0; i2 < 4; ++i2) {
    int row = bm + (ty<<2) + i2;
    #pragma unroll
    for (int j2 = 0; j2 < 4; ++j2) {
      int col = bn + (tx<<2) + j2;
      if (col < N) C[(size_t)row*N + col] = acc[i2][j2];
    }
  }
}

// -------- depthwise causal conv(4) + silu (+ optional l2norm); f32 and/or bf16 out --------
__global__ __launch_bounds__(256) void conv_silu(const float* __restrict__ X,
    const float* __restrict__ W, float* __restrict__ Yf, ushort* __restrict__ Yb,
    int mode, int ldx)
{
  int row = blockIdx.x;
  int b = row >> 10, t = row & 1023;
  int tid = threadIdx.x;
  int c0 = tid << 2;
  float w[4][4];
  #pragma unroll
  for (int c = 0; c < 4; ++c) {
    float4 wv = *(const float4*)&W[(c0 + c)*4];
    w[c][0]=wv.x; w[c][1]=wv.y; w[c][2]=wv.z; w[c][3]=wv.w;
  }
  float acc[4] = {0.f,0.f,0.f,0.f};
  #pragma unroll
  for (int j = 0; j < 4; ++j) {
    int tt = t - 3 + j;
    if (tt >= 0) {
      float4 xv = *(const float4*)&X[(size_t)(b*1024 + tt)*ldx + c0];
      acc[0] += w[0][j]*xv.x; acc[1] += w[1][j]*xv.y;
      acc[2] += w[2][j]*xv.z; acc[3] += w[3][j]*xv.w;
    }
  }
  #pragma unroll
  for (int c = 0; c < 4; ++c) acc[c] *= sigm(acc[c]);
  if (mode < 2) {
    float ss = acc[0]*acc[0]+acc[1]*acc[1]+acc[2]*acc[2]+acc[3]*acc[3];
    ss += __shfl_xor(ss, 1); ss += __shfl_xor(ss, 2); ss += __shfl_xor(ss, 4);
    ss += __shfl_xor(ss, 8); ss += __shfl_xor(ss, 16);
    float r = rsqrtf(ss + 1e-6f);
    if (mode == 0) r *= SCALE_Q;
    acc[0]*=r; acc[1]*=r; acc[2]*=r; acc[3]*=r;
  }
  size_t o = (size_t)(b*1024 + t)*1024 + c0;
  if (mode != 0) {
    float4 yv; yv.x=acc[0]; yv.y=acc[1]; yv.z=acc[2]; yv.w=acc[3];
    *(float4*)&Yf[o] = yv;
  }
  if (mode != 2) {
    ushort4 yb; yb.x=f2b(acc[0]); yb.y=f2b(acc[1]); yb.z=f2b(acc[2]); yb.w=f2b(acc[3]);
    *(ushort4*)&Yb[o] = yb;
  }
}

// -------- per-(b,h) log-decay cumsum, one block per bh --------
__global__ __launch_bounds__(256) void gc2(const float* __restrict__ xs,
    const float* __restrict__ A_log, const float* __restrict__ dt_bias,
    float* __restrict__ gc)
{
  int bh = blockIdx.x, b = bh >> 3, h = bh & 7;
  __shared__ float sc[256];
  int tid = threadIdx.x;
  float aexp = __expf(A_log[h]), db = dt_bias[h];
  int t0 = tid*4;
  float g[4], csum = 0.f;
  #pragma unroll
  for (int z = 0; z < 4; ++z) {
    float zv = xs[(size_t)(b*1024 + t0 + z)*104 + 8 + h] + db;
    float sp = (zv > 20.f) ? zv : log1pf(__expf(zv));
    csum += -aexp*sp;
    g[z] = csum;
  }
  sc[tid] = csum;
  __syncthreads();
  for (int ofs = 1; ofs < 256; ofs <<= 1) {
    float v = (tid >= ofs) ? sc[tid-ofs] : 0.f;
    __syncthreads();
    sc[tid] += v;
    __syncthreads();
  }
  float excl = sc[tid] - csum;
  #pragma unroll
  for (int z = 0; z < 4; ++z) gc[bh*1024 + t0 + z] = excl + g[z];
}

// -------- chunk prep: per (bh,chunk of 64): A, in-register fwd substitution --------
__global__ __launch_bounds__(256) void chunk_prep(const float* __restrict__ Kg,
    const float* __restrict__ Vg, const float* __restrict__ xs,
    const float* __restrict__ gcg, float* __restrict__ cw, float* __restrict__ cWk,
    float* __restrict__ cKp, float* __restrict__ eD)
{
  int blk = blockIdx.x;
  int bh = blk >> 4, ck = blk & 15;
  int b = bh >> 3, h = bh & 7;
  int a = ck << 6;
  __shared__ float Kc[64][132];
  __shared__ float As[64][68];
  __shared__ float gcl[65];
  __shared__ float bl[64];
  __shared__ float egc[64];
  __shared__ float edt[64];
  int tid = threadIdx.x;
  for (int e = tid; e < 64*32; e += 256) {
    int t = e >> 5, c4 = (e & 31) << 2;
    *(float4*)&Kc[t][c4] = *(const float4*)&Kg[(size_t)(b*1024 + a + t)*1024 + h*128 + c4];
  }
  if (tid < 64) {
    gcl[tid] = gcg[bh*1024 + a + tid];
    bl[tid] = sigm(xs[(size_t)(b*1024 + a + tid)*104 + h]);
  }
  if (tid == 64) gcl[64] = (ck < 15) ? gcg[bh*1024 + a + 64] : 0.f;
  __syncthreads();
  if (tid < 64) {
    egc[tid] = __expf(gcl[tid] - gcl[0]);
    edt[tid] = (ck < 15) ? __expf(gcl[64] - gcl[tid]) : 0.f;
  }
  {
    int ti = tid >> 4, si = tid & 15;
    if (si <= ti) {
      float dot[4][4] = {};
      for (int kk = 0; kk < 128; kk += 4) {
        float4 kt[4], ks[4];
        #pragma unroll
        for (int z = 0; z < 4; ++z) kt[z] = *(float4*)&Kc[ti*4+z][kk];
        #pragma unroll
        for (int z = 0; z < 4; ++z) ks[z] = *(float4*)&Kc[si*4+z][kk];
        #pragma unroll
        for (int i = 0; i < 4; ++i)
          #pragma unroll
          for (int j = 0; j < 4; ++j)
            dot[i][j] += kt[i].x*ks[j].x + kt[i].y*ks[j].y + kt[i].z*ks[j].z + kt[i].w*ks[j].w;
      }
      #pragma unroll
      for (int i = 0; i < 4; ++i) {
        int t = ti*4 + i;
        #pragma unroll
        for (int j = 0; j < 4; ++j) {
          int s = si*4 + j;
          if (s < t) As[t][s] = bl[t]*dot[i][j]*__expf(gcl[t]-gcl[s]);
        }
      }
    }
  }
  __syncthreads();
  int c = tid;
  float u[64];
  if (c < 128) {
    #pragma unroll
    for (int t = 0; t < 64; ++t)
      u[t] = bl[t]*Vg[(size_t)(b*1024 + a + t)*1024 + h*128 + c];
  } else {
    int d = c - 128;
    #pragma unroll
    for (int t = 0; t < 64; ++t)
      u[t] = bl[t]*egc[t]*Kc[t][d];
  }
  #pragma unroll
  for (int t = 1; t < 64; ++t) {
    float acc = u[t];
    int s = 0;
    #pragma unroll
    for (; s + 4 <= t; s += 4) {
      float4 a4 = *(float4*)&As[t][s];
      acc -= a4.x*u[s] + a4.y*u[s+1] + a4.z*u[s+2] + a4.w*u[s+3];
    }
    #pragma unroll
    for (; s < t; ++s) acc -= As[t][s]*u[s];
    u[t] = acc;
  }
  size_t cbase = (size_t)blk*8192;
  if (c < 128) {
    #pragma unroll
    for (int t = 0; t < 64; ++t)
      cw[cbase + t*128 + c] = u[t];
  } else {
    int d = c - 128;
    #pragma unroll
    for (int t = 0; t < 64; ++t) {
      cWk[cbase + t*128 + d] = u[t];
      cKp[cbase + t*128 + d] = Kc[t][d]*edt[t];
    }
  }
  if (tid == 0) eD[blk] = (ck < 15) ? __expf(gcl[64]-gcl[0]) : 0.f;
}

// -------- chunk scan v2: 256 blocks = 16 dv-slices(8 cols) x 16 bh --------
__global__ __launch_bounds__(256) void chunk_scan2(const float* __restrict__ cw,
    const float* __restrict__ cWk, const float* __restrict__ cKp,
    const float* __restrict__ eD, ushort* __restrict__ Ut)
{
  int blk = blockIdx.x;
  int slice = blk >> 4, bh = blk & 15;
  int e_base = slice << 3;
  __shared__ float Wks[2][8192];   // [64][128] f32 per buffer, swizzled cols
  __shared__ float Kps[2][8192];
  __shared__ float St[8][132];     // S transposed [e][k]
  __shared__ float us[64][9];
  int tid = threadIdx.x;
  float* stf = &St[0][0];
  for (int idx = tid; idx < 8*132; idx += 256) stf[idx] = 0.f;

  int tu = tid >> 2, e0 = (tid & 3) << 1;   // u-phase: (t, e-pair)
  int swu = tu & 7;
  int es = tid >> 5, k4 = tid & 31;         // S-phase: (e, k-quad)

  int ci0 = bh << 4;
  float2 wv = *(const float2*)&cw[(size_t)ci0*8192 + tu*128 + e_base + e0];
  {
    const char* wg = (const char*)(cWk + (size_t)ci0*8192);
    const char* kg = (const char*)(cKp + (size_t)ci0*8192);
    #pragma unroll
    for (int j = 0; j < 8; ++j) {
      unsigned off = (j<<12) + (tid<<4);
      unsigned so = off ^ ((((off>>9)&7u))<<4);
      __builtin_amdgcn_global_load_lds((const __attribute__((address_space(1))) unsigned*)(wg + so),
        (__attribute__((address_space(3))) unsigned*)((char*)&Wks[0][0] + off), 16, 0, 0);
      __builtin_amdgcn_global_load_lds((const __attribute__((address_space(1))) unsigned*)(kg + so),
        (__attribute__((address_space(3))) unsigned*)((char*)&Kps[0][0] + off), 16, 0, 0);
    }
  }
  __syncthreads();

  for (int i = 0; i < 16; ++i) {
    int ci = ci0 + i, a = i << 6, cur = i & 1;
    float2 wv_next;
    if (i < 15) {
      wv_next = *(const float2*)&cw[(size_t)(ci+1)*8192 + tu*128 + e_base + e0];
      const char* wg = (const char*)(cWk + (size_t)(ci+1)*8192);
      const char* kg = (const char*)(cKp + (size_t)(ci+1)*8192);
      char* wl = (char*)&Wks[cur^1][0];
      char* kl = (char*)&Kps[cur^1][0];
      #pragma unroll
      for (int j = 0; j < 8; ++j) {
        unsigned off = (j<<12) + (tid<<4);
        unsigned so = off ^ ((((off>>9)&7u))<<4);
        __builtin_amdgcn_global_load_lds((const __attribute__((address_space(1))) unsigned*)(wg + so),
          (__attribute__((address_space(3))) unsigned*)(wl + off), 16, 0, 0);
        __builtin_amdgcn_global_load_lds((const __attribute__((address_space(1))) unsigned*)(kg + so),
          (__attribute__((address_space(3))) unsigned*)(kl + off), 16, 0, 0);
      }
    }
    {
      float acc0 = wv.x, acc1 = wv.y;
      const char* wb = (const char*)&Wks[cur][0];
      const f32x4* s0p = (const f32x4*)&St[e0][0];
      const f32x4* s1p = (const f32x4*)&St[e0+1][0];
      #pragma unroll 8
      for (int k = 0; k < 32; ++k) {
        f32x4 wk = *(const f32x4*)(wb + (tu<<9) + ((k ^ swu)<<4));
        f32x4 s0 = s0p[k];
        f32x4 s1 = s1p[k];
        acc0 -= wk[0]*s0[0] + wk[1]*s0[1] + wk[2]*s0[2] + wk[3]*s0[3];
        acc1 -= wk[0]*s1[0] + wk[1]*s1[1] + wk[2]*s1[2] + wk[3]*s1[3];
      }
      us[tu][e0]   = acc0;
      us[tu][e0+1] = acc1;
      size_t ur = (size_t)(bh*128 + e_base + e0)*1024 + a + tu;
      Ut[ur]        = f2b(acc0);
      Ut[ur + 1024] = f2b(acc1);
    }
    __syncthreads();
    if (i < 15) {
      float ed = eD[ci];
      f32x4 sa = ed * *(f32x4*)&St[es][k4<<2];
      const char* kb = (const char*)&Kps[cur][0];
      #pragma unroll 8
      for (int t = 0; t < 64; ++t) {
        f32x4 kp = *(const f32x4*)(kb + (t<<9) + ((k4 ^ (t&7))<<4));
        float uv = us[t][es];
        sa += kp * uv;
      }
      *(f32x4*)&St[es][k4<<2] = sa;
      wv = wv_next;
    }
    __syncthreads();
  }
}

// -------- MFMA log-linear readout v3: LDS-staged K/Ut, double-buffered --------
// grid (x: 16bh x 16 qchunks of 64, y: 2 s-halves). 4 waves x 16 q-rows.
// Per j-step: stage K(64x128 bf16, swz c16^=row&15) + Ut(128x64 bf16, swz c16^=d&7)
// via global_load_lds (pre-swizzled source, linear LDS dest); stage j+1 issued
// BEFORE compute j; one __syncthreads per step drains it (T3 2-phase recipe).
__global__ __launch_bounds__(256) void readout3(const ushort* __restrict__ Qb,
    const ushort* __restrict__ Kb, const ushort* __restrict__ Ut,
    const float* __restrict__ gcg, const float* __restrict__ xs,
    float* __restrict__ Og)
{
  int blk = blockIdx.x;
  int bh = blk >> 4, ic = blk & 15;
  int half = blockIdx.y;
  int b = bh >> 3, h = bh & 7;
  int tbase = ic << 6;
  __shared__ ushort Ks[2][8192];       // 16 KB: 64 rows x 256B, col16 ^= row&15
  __shared__ ushort Us[2][8192];       // 16 KB: 128 rows x 128B, col16 ^= d&7
  __shared__ ushort Pl[4][1024];       // 16x64 bf16 per wave, XOR-swizzled
  __shared__ float lamS[64][12];
  int tid = threadIdx.x;
  int wave = tid >> 6, lane = tid & 63;
  int l15 = lane & 15, kh = lane >> 4;

  const char* kgb = (const char*)Kb + ((size_t)(b*1024)*1024 + h*128)*2;
  const char* ugb = (const char*)Ut + ((size_t)(bh*128)*1024)*2;

  for (int e = tid; e < 64*11; e += 256) {
    int t = e/11, l = e%11;
    lamS[t][l] = sigm(xs[(size_t)(b*1024+tbase+t)*104 + 16 + h*11 + l]);
  }
  int tl = kh*4;
  float gct_r[4];
  #pragma unroll
  for (int r = 0; r < 4; ++r) gct_r[r] = gcg[bh*1024 + tbase + wave*16 + tl + r];
  bf16x8 qf[4];
  {
    const ushort* qp = &Qb[(size_t)(b*1024 + tbase + wave*16 + l15)*1024 + h*128 + kh*8];
    #pragma unroll
    for (int kk = 0; kk < 4; ++kk) qf[kk] = *(const bf16x8*)(qp + kk*32);
  }

  f32x4 accO[8] = {};
  int nsteps = ic + 1;
  int jmid = (nsteps + 1) >> 1;
  int j0 = half ? jmid : 0;
  int j1 = half ? nsteps : jmid;
  ushort* Pw = &Pl[wave][0];

  if (j0 < j1) {
    // prologue: stage chunk j0 into buffer 0
    {
      const char* kg = kgb + (size_t)(j0<<6)*2048;
      const char* ug = ugb + (size_t)(j0<<6)*2;
      #pragma unroll
      for (int it = 0; it < 4; ++it) {
        unsigned off = (it<<12) + (tid<<4);
        unsigned krow = off >> 8, kc = (off >> 4) & 15;
        unsigned ksrc = krow*2048 + ((kc ^ (krow & 15)) << 4);
        __builtin_amdgcn_global_load_lds((const __attribute__((address_space(1))) unsigned*)(kg + ksrc),
          (__attribute__((address_space(3))) unsigned*)((char*)&Ks[0][0] + off), 16, 0, 0);
        unsigned ud = off >> 7, uc = (off >> 4) & 7;
        unsigned usrc = ud*2048 + ((uc ^ (ud & 7)) << 4);
        __builtin_amdgcn_global_load_lds((const __attribute__((address_space(1))) unsigned*)(ug + usrc),
          (__attribute__((address_space(3))) unsigned*)((char*)&Us[0][0] + off), 16, 0, 0);
      }
    }
    __syncthreads();
    int cur = 0;
    for (int j = j0; j < j1; ++j) {
      int sbase = j << 6;
      // issue next-chunk staging first (latency hides under compute)
      if (j + 1 < j1) {
        const char* kg = kgb + (size_t)((j+1)<<6)*2048;
        const char* ug = ugb + (size_t)((j+1)<<6)*2;
        char* kl = (char*)&Ks[cur^1][0];
        char* ul = (char*)&Us[cur^1][0];
        #pragma unroll
        for (int it = 0; it < 4; ++it) {
          unsigned off = (it<<12) + (tid<<4);
          unsigned krow = off >> 8, kc = (off >> 4) & 15;
          unsigned ksrc = krow*2048 + ((kc ^ (krow & 15)) << 4);
          __builtin_amdgcn_global_load_lds((const __attribute__((address_space(1))) unsigned*)(kg + ksrc),
            (__attribute__((address_space(3))) unsigned*)(kl + off), 16, 0, 0);
          unsigned ud = off >> 7, uc = (off >> 4) & 7;
          unsigned usrc = ud*2048 + ((uc ^ (ud & 7)) << 4);
          __builtin_amdgcn_global_load_lds((const __attribute__((address_space(1))) unsigned*)(ug + usrc),
            (__attribute__((address_space(3))) unsigned*)(ul + off), 16, 0, 0);
        }
      }
      float gcs_r[4];
      #pragma unroll
      for (int jt = 0; jt < 4; ++jt)
        gcs_r[jt] = gcg[bh*1024 + sbase + jt*16 + l15];
      // QK^T from LDS
      f32x4 accS[4] = {};
      const char* ksb = (const char*)&Ks[cur][0];
      #pragma unroll
      for (int jt = 0; jt < 4; ++jt) {
        int row = jt*16 + l15;
        int rsw = row & 15;
        #pragma unroll
        for (int kk = 0; kk < 4; ++kk) {
          bf16x8 kf = *(const bf16x8*)(ksb + row*256 + (((kk*4 + kh) ^ rsw) << 4));
          accS[jt] = __builtin_amdgcn_mfma_f32_16x16x32_bf16(qf[kk], kf, accS[jt], 0, 0, 0);
        }
      }
      // decay * lam[level] -> P (bf16, per-wave swizzled LDS)
      #pragma unroll
      for (int jt = 0; jt < 4; ++jt) {
        int sg = sbase + jt*16 + l15;
        #pragma unroll
        for (int r = 0; r < 4; ++r) {
          int t_loc = tl + r;
          int tg = tbase + wave*16 + t_loc;
          float pv = 0.f;
          if (sg <= tg) {
            int lev = 31 - __clz((unsigned)((tg+1) ^ sg));
            lev = lev > 10 ? 10 : lev;
            pv = accS[jt][r] * __expf(gct_r[r] - gcs_r[jt]) * lamS[wave*16 + t_loc][lev];
          }
          int bo = (t_loc << 7) + ((jt*16 + l15) << 1);
          bo ^= (t_loc & 7) << 4;
          *(ushort*)((char*)Pw + bo) = f2b(pv);
        }
      }
      // PV from LDS
      const char* usb = (const char*)&Us[cur][0];
      #pragma unroll
      for (int ks = 0; ks < 2; ++ks) {
        int bo = (l15 << 7) + ((ks*32 + kh*8) << 1);
        bo ^= (l15 & 7) << 4;
        bf16x8 pa = *(bf16x8*)((char*)Pw + bo);
        #pragma unroll
        for (int dt = 0; dt < 8; ++dt) {
          int d = dt*16 + l15;
          bf16x8 uf = *(const bf16x8*)(usb + d*128 + (((ks*4 + kh) ^ (d & 7)) << 4));
          accO[dt] = __builtin_amdgcn_mfma_f32_16x16x32_bf16(pa, uf, accO[dt], 0, 0, 0);
        }
      }
      __syncthreads();   // drains staging of j+1; all waves done with buf cur
      cur ^= 1;
    }
  }
  float* og = Og + (size_t)half*2097152;
  #pragma unroll
  for (int dt = 0; dt < 8; ++dt) {
    #pragma unroll
    for (int r = 0; r < 4; ++r) {
      int row = tbase + wave*16 + tl + r;
      og[(size_t)(b*1024 + row)*1024 + h*128 + dt*16 + l15] = accO[dt][r];
    }
  }
}

// -------- gated RMSNorm (sums two partial O buffers) -> bf16 --------
__global__ __launch_bounds__(64) void normgate(const float* __restrict__ O1,
    const float* __restrict__ O2, const float* __restrict__ G,
    const float* __restrict__ norm_w, ushort* __restrict__ Y)
{
  int row = blockIdx.x;
  int lane = threadIdx.x;
  size_t base = (size_t)(row >> 3)*1024 + (size_t)(row & 7)*128;
  float2 oa = *(const float2*)&O1[base + lane*2];
  float2 ob = *(const float2*)&O2[base + lane*2];
  float ox = oa.x + ob.x, oy = oa.y + ob.y;
  float ss = ox*ox + oy*oy;
  #pragma unroll
  for (int m = 1; m < 64; m <<= 1) ss += __shfl_xor(ss, m);
  float r = rsqrtf(ss * (1.f/128.f) + 1e-5f);
  float2 g = *(const float2*)&G[base + lane*2];
  ushort2 y;
  y.x = f2b(ox * r * norm_w[lane*2+0] * (g.x * sigm(g.x)));
  y.y = f2b(oy * r * norm_w[lane*2+1] * (g.y * sigm(g.y)));
  *(ushort2*)&Y[base + lane*2] = y;
}

extern "C" void kernel_launch(void* const* d_in, const int* in_sizes, int n_in,
                              void* d_out, int out_size, void* d_ws, size_t ws_size,
                              hipStream_t stream)
{
  const float* x    = (const float*)d_in[0];
  const float* Wq   = (const float*)d_in[3];
  const float* Wk   = (const float*)d_in[4];
  const float* Wv   = (const float*)d_in[5];
  const float* Wb   = (const float*)d_in[6];
  const float* Wa   = (const float*)d_in[7];
  const float* Wl   = (const float*)d_in[8];
  const float* Wg   = (const float*)d_in[9];
  const float* Wo   = (const float*)d_in[10];
  const float* cq   = (const float*)d_in[11];
  const float* ck   = (const float*)d_in[12];
  const float* cv   = (const float*)d_in[13];
  const float* A_log   = (const float*)d_in[14];
  const float* dt_bias = (const float*)d_in[15];
  const float* norm_w  = (const float*)d_in[16];
  float* out = (float*)d_out;

  float* p = (float*)d_ws;
  float* xqkv = p;  p += 6291456;            // [2048][3072] f32 (dead after convs)
  float* xg   = p;  p += 2097152;
  float* kb   = p;  p += 2097152;
  float* vb   = p;  p += 2097152;
  float* o1   = p;  p += 2097152;            // o1,o2 MUST be adjacent (readout3 half offset)
  float* o2   = p;  p += 2097152;
  float* xs   = p;  p += 212992;
  float* gc   = p;  p += 16384;
  float* eD   = p;  p += 256;
  // NOTE: p is float*; every 2M-ushort (4MB) bf16 buffer needs p += 1048576
  ushort* x16 = (ushort*)p; p += 1048576;    // [2048][1024] bf16
  ushort* Wt4 = (ushort*)p; p += 2097152;    // [4096][1024] bf16
  ushort* Wot = (ushort*)p; p += 524288;     // [1024][1024] bf16
  float* Wsm  = p;  p += 106496;
  ushort* yb16= (ushort*)p; p += 1048576;    // [2048][1024] bf16
  ushort* qb16= (ushort*)p; p += 1048576;    // [2048][1024] bf16
  ushort* kb16= (ushort*)p; p += 1048576;    // [2048][1024] bf16
  ushort* ut16= (ushort*)p; p += 1048576;    // [16*128][1024] bf16
  float* cw  = xqkv;                          // overlay dead xqkv
  float* cWk = xqkv + 2097152;
  float* cKp = xqkv + 4194304;

  dim3 blk(256);
  cast_x<<<dim3(2048), blk, 0, stream>>>(x, x16);
  transcast<<<dim3(32,32), blk, 0, stream>>>(Wq, Wt4);
  transcast<<<dim3(32,32), blk, 0, stream>>>(Wk, Wt4 + 1024*1024);
  transcast<<<dim3(32,32), blk, 0, stream>>>(Wv, Wt4 + 2*1024*1024);
  transcast<<<dim3(32,32), blk, 0, stream>>>(Wg, Wt4 + 3*1024*1024);
  transcast<<<dim3(32,32), blk, 0, stream>>>(Wo, Wot);
  copy_wsmall<<<dim3(416), blk, 0, stream>>>(Wb, Wa, Wl, Wsm);
  gemm_bf16<<<dim3(32,16), blk, 0, stream>>>(x16, Wt4, xqkv, xg, 2048, 4096, 1024,
                                             3072, 3072, 1024);
  gemm_f32<<<dim3(2,32), blk, 0, stream>>>(x, Wsm, xs, 2048, 104, 1024);
  conv_silu<<<dim3(2048), blk, 0, stream>>>(xqkv + 0,    cq, nullptr, qb16, 0, 3072);
  conv_silu<<<dim3(2048), blk, 0, stream>>>(xqkv + 1024, ck, kb, kb16, 1, 3072);
  conv_silu<<<dim3(2048), blk, 0, stream>>>(xqkv + 2048, cv, vb, nullptr, 2, 3072);
  gc2<<<dim3(16), blk, 0, stream>>>(xs, A_log, dt_bias, gc);
  chunk_prep<<<dim3(256), blk, 0, stream>>>(kb, vb, xs, gc, cw, cWk, cKp, eD);
  chunk_scan2<<<dim3(256), blk, 0, stream>>>(cw, cWk, cKp, eD, ut16);
  readout3<<<dim3(256,2), blk, 0, stream>>>(qb16, kb16, ut16, gc, xs, o1);
  normgate<<<dim3(16384), dim3(64), 0, stream>>>(o1, o2, xg, norm_w, yb16);
  gemm_bf16<<<dim3(8,16), blk, 0, stream>>>(yb16, Wot, out, out, 2048, 1024, 1024,
                                            1024, 1024, 1024);
}

// Round 7
// 252.960 us; speedup vs baseline: 9.7073x; 1.2059x over previous
//
#include <hip/hip_runtime.h>
#include <hip/hip_bf16.h>
#include <math.h>

// B=2, T=1024, D=1024, H=8, Dh=128, L=11, conv=4; chunk C=64, 16 chunks/bh
#define SCALE_Q 0.08838834764831845f

typedef __bf16 bf16x8 __attribute__((ext_vector_type(8)));
typedef float f32x4 __attribute__((ext_vector_type(4)));

static __device__ __forceinline__ float sigm(float x){ return 1.f/(1.f+__expf(-x)); }
static __device__ __forceinline__ ushort f2b(float v){
  __hip_bfloat16 t = __float2bfloat16(v);
  return __builtin_bit_cast(ushort, t);
}

// ---------------- cast x f32 -> bf16 ----------------
__global__ __launch_bounds__(256) void cast_x(const float* __restrict__ X,
    ushort* __restrict__ Y)
{
  int idx = blockIdx.x*256 + threadIdx.x;
  float4 v = *(const float4*)&X[(size_t)idx*4];
  ushort4 o; o.x=f2b(v.x); o.y=f2b(v.y); o.z=f2b(v.z); o.w=f2b(v.w);
  *(ushort4*)&Y[(size_t)idx*4] = o;
}

// ---------------- transpose + cast: Wt[n][k] = bf16(W[k][n]), 1024x1024 ----------------
__global__ __launch_bounds__(256) void transcast(const float* __restrict__ W,
    ushort* __restrict__ Wt)
{
  __shared__ float tile[32][36];
  int n0 = blockIdx.x*32, k0 = blockIdx.y*32;
  int tid = threadIdx.x;
  int r = tid >> 3, c4 = (tid & 7) << 2;
  *(float4*)&tile[r][c4] = *(const float4*)&W[(size_t)(k0 + r)*1024 + n0 + c4];
  __syncthreads();
  ushort4 o;
  o.x = f2b(tile[c4+0][r]); o.y = f2b(tile[c4+1][r]);
  o.z = f2b(tile[c4+2][r]); o.w = f2b(tile[c4+3][r]);
  *(ushort4*)&Wt[(size_t)(n0 + r)*1024 + k0 + c4] = o;
}

// ---------------- concat small weights: Wsm[k][0:8]=Wb, [8:16]=Wa, [16:104]=Wl ----------------
__global__ __launch_bounds__(256) void copy_wsmall(const float* __restrict__ Wb,
    const float* __restrict__ Wa, const float* __restrict__ Wl, float* __restrict__ Wsm)
{
  int idx = blockIdx.x*256 + threadIdx.x;
  if (idx >= 1024*104) return;
  int k = idx / 104, c = idx % 104;
  float v = (c < 8) ? Wb[k*8+c] : (c < 16) ? Wa[k*8+(c-8)] : Wl[k*88+(c-16)];
  Wsm[idx] = v;
}

// ---------------- bf16 MFMA GEMM: C[M,N] = A[M,K] @ Bt[N,K]^T, C f32, split cols ----------------
__global__ __launch_bounds__(256) void gemm_bf16(const ushort* __restrict__ A,
    const ushort* __restrict__ Bt, float* __restrict__ C0, float* __restrict__ C1,
    int M, int N, int K, int nsplit, int ld0, int ld1)
{
  __shared__ ushort As[128*32];
  __shared__ ushort Bs[128*32];
  int tid = threadIdx.x;
  int bm = blockIdx.y * 128, bn = blockIdx.x * 128;
  int wave = tid >> 6, lane = tid & 63;
  int wm = (wave >> 1) * 64, wn = (wave & 1) * 64;
  int l16 = lane & 15, kh = lane >> 4;
  f32x4 acc[4][4] = {};
  int rowA0 = tid >> 2, boA = (tid & 3) * 16;
  for (int k0 = 0; k0 < K; k0 += 32) {
    #pragma unroll
    for (int j = 0; j < 2; ++j) {
      int row = rowA0 + j*64;
      const char* gA = (const char*)A + (((size_t)(bm+row)*K + k0)*2 + boA);
      const char* gB = (const char*)Bt + (((size_t)(bn+row)*K + k0)*2 + boA);
      __builtin_amdgcn_global_load_lds((const __attribute__((address_space(1))) unsigned*)gA,
        (__attribute__((address_space(3))) unsigned*)((char*)As + row*64 + boA), 16, 0, 0);
      __builtin_amdgcn_global_load_lds((const __attribute__((address_space(1))) unsigned*)gB,
        (__attribute__((address_space(3))) unsigned*)((char*)Bs + row*64 + boA), 16, 0, 0);
    }
    __syncthreads();
    bf16x8 af[4], bfr[4];
    #pragma unroll
    for (int i = 0; i < 4; ++i)
      af[i] = *(bf16x8*)((char*)As + (wm + i*16 + l16)*64 + kh*16);
    #pragma unroll
    for (int j = 0; j < 4; ++j)
      bfr[j] = *(bf16x8*)((char*)Bs + (wn + j*16 + l16)*64 + kh*16);
    #pragma unroll
    for (int i = 0; i < 4; ++i)
      #pragma unroll
      for (int j = 0; j < 4; ++j)
        acc[i][j] = __builtin_amdgcn_mfma_f32_16x16x32_bf16(af[i], bfr[j], acc[i][j], 0, 0, 0);
    __syncthreads();
  }
  int rg = lane >> 4;
  #pragma unroll
  for (int i = 0; i < 4; ++i) {
    #pragma unroll
    for (int j = 0; j < 4; ++j) {
      int col = bn + wn + j*16 + l16;
      #pragma unroll
      for (int r = 0; r < 4; ++r) {
        int row = bm + wm + i*16 + rg*4 + r;
        float v = acc[i][j][r];
        if (col < nsplit) C0[(size_t)row*ld0 + col] = v;
        else              C1[(size_t)row*ld1 + (col - nsplit)] = v;
      }
    }
  }
}

// -------- skinny split-K GEMM: part[ks][M][104] = x[M,k0:k0+128] @ Wsm[k0:k0+128][104] --------
// grid (32 m-tiles of 64 rows, 8 k-slices of 128) = 256 blocks = 1/CU.
__global__ __launch_bounds__(256) void skinny104(const float* __restrict__ X,
    const float* __restrict__ Wsm, float* __restrict__ part)
{
  __shared__ float XL[64][132];     // pad 132: xv banks (row+k)%32 -> conflict-free
  __shared__ float WsL[128][112];   // cols 104..111 zero-padded; 28-col strips 16B-aligned
  int tid = threadIdx.x;
  int m0 = blockIdx.x << 6;
  int k0 = blockIdx.y << 7;
  // stage X tile: 2048 float4 slots
  #pragma unroll
  for (int j = 0; j < 8; ++j) {
    int s = tid + j*256;
    int row = s >> 5, c4 = (s & 31) << 2;
    *(float4*)&XL[row][c4] = *(const float4*)&X[(size_t)(m0 + row)*1024 + k0 + c4];
  }
  // zero the pad cols
  {
    int k = tid >> 1, c = 104 + ((tid & 1) << 2);
    *(float4*)&WsL[k][c] = (float4){0.f,0.f,0.f,0.f};
    *(float4*)&WsL[k+128 <= 127 ? k : k][c] = *(float4*)&WsL[k][c]; // no-op guard
  }
  // stage Ws slice: 2 threads per row, 13 float4 each
  {
    int k = tid >> 1, cb = (tid & 1) * 52;
    #pragma unroll
    for (int j = 0; j < 13; ++j) {
      *(float4*)&WsL[k][cb + j*4] = *(const float4*)&Wsm[(size_t)(k0 + k)*104 + cb + j*4];
    }
  }
  __syncthreads();
  int row = tid >> 2, cq = tid & 3;
  int cbase = cq * 28;
  f32x4 acc[7] = {};
  const float* xrow = &XL[row][0];
  #pragma unroll 4
  for (int k = 0; k < 128; ++k) {
    float xv = xrow[k];
    const f32x4* wr = (const f32x4*)&WsL[k][cbase];
    #pragma unroll
    for (int j = 0; j < 7; ++j) acc[j] += xv * wr[j];
  }
  float* pr = &part[((size_t)blockIdx.y*2048 + m0 + row)*104 + cbase];
  int nst = (cq == 3) ? 5 : 7;   // cq=3 covers cols 84..103 (20 = 5 float4)
  for (int j = 0; j < nst; ++j) *(f32x4*)&pr[j*4] = acc[j];
}

// -------- reduce 8 K-slice partials -> xs[2048][104] --------
__global__ __launch_bounds__(256) void reduce8(const float* __restrict__ part,
    float* __restrict__ xs)
{
  int idx = blockIdx.x*256 + threadIdx.x;   // 833*256 == 213248 == 2048*104 exactly
  float s = 0.f;
  #pragma unroll
  for (int i = 0; i < 8; ++i) s += part[(size_t)i*212992 + idx];
  xs[idx] = s;
}

// -------- depthwise causal conv(4) + silu (+ optional l2norm); f32 and/or bf16 out --------
__global__ __launch_bounds__(256) void conv_silu(const float* __restrict__ X,
    const float* __restrict__ W, float* __restrict__ Yf, ushort* __restrict__ Yb,
    int mode, int ldx)
{
  int row = blockIdx.x;
  int b = row >> 10, t = row & 1023;
  int tid = threadIdx.x;
  int c0 = tid << 2;
  float w[4][4];
  #pragma unroll
  for (int c = 0; c < 4; ++c) {
    float4 wv = *(const float4*)&W[(c0 + c)*4];
    w[c][0]=wv.x; w[c][1]=wv.y; w[c][2]=wv.z; w[c][3]=wv.w;
  }
  float acc[4] = {0.f,0.f,0.f,0.f};
  #pragma unroll
  for (int j = 0; j < 4; ++j) {
    int tt = t - 3 + j;
    if (tt >= 0) {
      float4 xv = *(const float4*)&X[(size_t)(b*1024 + tt)*ldx + c0];
      acc[0] += w[0][j]*xv.x; acc[1] += w[1][j]*xv.y;
      acc[2] += w[2][j]*xv.z; acc[3] += w[3][j]*xv.w;
    }
  }
  #pragma unroll
  for (int c = 0; c < 4; ++c) acc[c] *= sigm(acc[c]);
  if (mode < 2) {
    float ss = acc[0]*acc[0]+acc[1]*acc[1]+acc[2]*acc[2]+acc[3]*acc[3];
    ss += __shfl_xor(ss, 1); ss += __shfl_xor(ss, 2); ss += __shfl_xor(ss, 4);
    ss += __shfl_xor(ss, 8); ss += __shfl_xor(ss, 16);
    float r = rsqrtf(ss + 1e-6f);
    if (mode == 0) r *= SCALE_Q;
    acc[0]*=r; acc[1]*=r; acc[2]*=r; acc[3]*=r;
  }
  size_t o = (size_t)(b*1024 + t)*1024 + c0;
  if (mode != 0) {
    float4 yv; yv.x=acc[0]; yv.y=acc[1]; yv.z=acc[2]; yv.w=acc[3];
    *(float4*)&Yf[o] = yv;
  }
  if (mode != 2) {
    ushort4 yb; yb.x=f2b(acc[0]); yb.y=f2b(acc[1]); yb.z=f2b(acc[2]); yb.w=f2b(acc[3]);
    *(ushort4*)&Yb[o] = yb;
  }
}

// -------- per-(b,h) log-decay cumsum, one block per bh --------
__global__ __launch_bounds__(256) void gc2(const float* __restrict__ xs,
    const float* __restrict__ A_log, const float* __restrict__ dt_bias,
    float* __restrict__ gc)
{
  int bh = blockIdx.x, b = bh >> 3, h = bh & 7;
  __shared__ float sc[256];
  int tid = threadIdx.x;
  float aexp = __expf(A_log[h]), db = dt_bias[h];
  int t0 = tid*4;
  float g[4], csum = 0.f;
  #pragma unroll
  for (int z = 0; z < 4; ++z) {
    float zv = xs[(size_t)(b*1024 + t0 + z)*104 + 8 + h] + db;
    float sp = (zv > 20.f) ? zv : log1pf(__expf(zv));
    csum += -aexp*sp;
    g[z] = csum;
  }
  sc[tid] = csum;
  __syncthreads();
  for (int ofs = 1; ofs < 256; ofs <<= 1) {
    float v = (tid >= ofs) ? sc[tid-ofs] : 0.f;
    __syncthreads();
    sc[tid] += v;
    __syncthreads();
  }
  float excl = sc[tid] - csum;
  #pragma unroll
  for (int z = 0; z < 4; ++z) gc[bh*1024 + t0 + z] = excl + g[z];
}

// -------- chunk prep: per (bh,chunk of 64): A, in-register fwd substitution --------
__global__ __launch_bounds__(256) void chunk_prep(const float* __restrict__ Kg,
    const float* __restrict__ Vg, const float* __restrict__ xs,
    const float* __restrict__ gcg, float* __restrict__ cw, float* __restrict__ cWk,
    float* __restrict__ cKp, float* __restrict__ eD)
{
  int blk = blockIdx.x;
  int bh = blk >> 4, ck = blk & 15;
  int b = bh >> 3, h = bh & 7;
  int a = ck << 6;
  __shared__ float Kc[64][132];
  __shared__ float As[64][68];
  __shared__ float gcl[65];
  __shared__ float bl[64];
  __shared__ float egc[64];
  __shared__ float edt[64];
  int tid = threadIdx.x;
  for (int e = tid; e < 64*32; e += 256) {
    int t = e >> 5, c4 = (e & 31) << 2;
    *(float4*)&Kc[t][c4] = *(const float4*)&Kg[(size_t)(b*1024 + a + t)*1024 + h*128 + c4];
  }
  if (tid < 64) {
    gcl[tid] = gcg[bh*1024 + a + tid];
    bl[tid] = sigm(xs[(size_t)(b*1024 + a + tid)*104 + h]);
  }
  if (tid == 64) gcl[64] = (ck < 15) ? gcg[bh*1024 + a + 64] : 0.f;
  __syncthreads();
  if (tid < 64) {
    egc[tid] = __expf(gcl[tid] - gcl[0]);
    edt[tid] = (ck < 15) ? __expf(gcl[64] - gcl[tid]) : 0.f;
  }
  {
    int ti = tid >> 4, si = tid & 15;
    if (si <= ti) {
      float dot[4][4] = {};
      for (int kk = 0; kk < 128; kk += 4) {
        float4 kt[4], ks[4];
        #pragma unroll
        for (int z = 0; z < 4; ++z) kt[z] = *(float4*)&Kc[ti*4+z][kk];
        #pragma unroll
        for (int z = 0; z < 4; ++z) ks[z] = *(float4*)&Kc[si*4+z][kk];
        #pragma unroll
        for (int i = 0; i < 4; ++i)
          #pragma unroll
          for (int j = 0; j < 4; ++j)
            dot[i][j] += kt[i].x*ks[j].x + kt[i].y*ks[j].y + kt[i].z*ks[j].z + kt[i].w*ks[j].w;
      }
      #pragma unroll
      for (int i = 0; i < 4; ++i) {
        int t = ti*4 + i;
        #pragma unroll
        for (int j = 0; j < 4; ++j) {
          int s = si*4 + j;
          if (s < t) As[t][s] = bl[t]*dot[i][j]*__expf(gcl[t]-gcl[s]);
        }
      }
    }
  }
  __syncthreads();
  int c = tid;
  float u[64];
  if (c < 128) {
    #pragma unroll
    for (int t = 0; t < 64; ++t)
      u[t] = bl[t]*Vg[(size_t)(b*1024 + a + t)*1024 + h*128 + c];
  } else {
    int d = c - 128;
    #pragma unroll
    for (int t = 0; t < 64; ++t)
      u[t] = bl[t]*egc[t]*Kc[t][d];
  }
  #pragma unroll
  for (int t = 1; t < 64; ++t) {
    float acc = u[t];
    int s = 0;
    #pragma unroll
    for (; s + 4 <= t; s += 4) {
      float4 a4 = *(float4*)&As[t][s];
      acc -= a4.x*u[s] + a4.y*u[s+1] + a4.z*u[s+2] + a4.w*u[s+3];
    }
    #pragma unroll
    for (; s < t; ++s) acc -= As[t][s]*u[s];
    u[t] = acc;
  }
  size_t cbase = (size_t)blk*8192;
  if (c < 128) {
    #pragma unroll
    for (int t = 0; t < 64; ++t)
      cw[cbase + t*128 + c] = u[t];
  } else {
    int d = c - 128;
    #pragma unroll
    for (int t = 0; t < 64; ++t) {
      cWk[cbase + t*128 + d] = u[t];
      cKp[cbase + t*128 + d] = Kc[t][d]*edt[t];
    }
  }
  if (tid == 0) eD[blk] = (ck < 15) ? __expf(gcl[64]-gcl[0]) : 0.f;
}

// -------- chunk scan v2: 256 blocks = 16 dv-slices(8 cols) x 16 bh --------
__global__ __launch_bounds__(256) void chunk_scan2(const float* __restrict__ cw,
    const float* __restrict__ cWk, const float* __restrict__ cKp,
    const float* __restrict__ eD, ushort* __restrict__ Ut)
{
  int blk = blockIdx.x;
  int slice = blk >> 4, bh = blk & 15;
  int e_base = slice << 3;
  __shared__ float Wks[2][8192];   // [64][128] f32 per buffer, swizzled cols
  __shared__ float Kps[2][8192];
  __shared__ float St[8][132];     // S transposed [e][k]
  __shared__ float us[64][9];
  int tid = threadIdx.x;
  float* stf = &St[0][0];
  for (int idx = tid; idx < 8*132; idx += 256) stf[idx] = 0.f;

  int tu = tid >> 2, e0 = (tid & 3) << 1;   // u-phase: (t, e-pair)
  int swu = tu & 7;
  int es = tid >> 5, k4 = tid & 31;         // S-phase: (e, k-quad)

  int ci0 = bh << 4;
  float2 wv = *(const float2*)&cw[(size_t)ci0*8192 + tu*128 + e_base + e0];
  {
    const char* wg = (const char*)(cWk + (size_t)ci0*8192);
    const char* kg = (const char*)(cKp + (size_t)ci0*8192);
    #pragma unroll
    for (int j = 0; j < 8; ++j) {
      unsigned off = (j<<12) + (tid<<4);
      unsigned so = off ^ ((((off>>9)&7u))<<4);
      __builtin_amdgcn_global_load_lds((const __attribute__((address_space(1))) unsigned*)(wg + so),
        (__attribute__((address_space(3))) unsigned*)((char*)&Wks[0][0] + off), 16, 0, 0);
      __builtin_amdgcn_global_load_lds((const __attribute__((address_space(1))) unsigned*)(kg + so),
        (__attribute__((address_space(3))) unsigned*)((char*)&Kps[0][0] + off), 16, 0, 0);
    }
  }
  __syncthreads();

  for (int i = 0; i < 16; ++i) {
    int ci = ci0 + i, a = i << 6, cur = i & 1;
    float2 wv_next;
    if (i < 15) {
      wv_next = *(const float2*)&cw[(size_t)(ci+1)*8192 + tu*128 + e_base + e0];
      const char* wg = (const char*)(cWk + (size_t)(ci+1)*8192);
      const char* kg = (const char*)(cKp + (size_t)(ci+1)*8192);
      char* wl = (char*)&Wks[cur^1][0];
      char* kl = (char*)&Kps[cur^1][0];
      #pragma unroll
      for (int j = 0; j < 8; ++j) {
        unsigned off = (j<<12) + (tid<<4);
        unsigned so = off ^ ((((off>>9)&7u))<<4);
        __builtin_amdgcn_global_load_lds((const __attribute__((address_space(1))) unsigned*)(wg + so),
          (__attribute__((address_space(3))) unsigned*)(wl + off), 16, 0, 0);
        __builtin_amdgcn_global_load_lds((const __attribute__((address_space(1))) unsigned*)(kg + so),
          (__attribute__((address_space(3))) unsigned*)(kl + off), 16, 0, 0);
      }
    }
    {
      float acc0 = wv.x, acc1 = wv.y;
      const char* wb = (const char*)&Wks[cur][0];
      const f32x4* s0p = (const f32x4*)&St[e0][0];
      const f32x4* s1p = (const f32x4*)&St[e0+1][0];
      #pragma unroll 8
      for (int k = 0; k < 32; ++k) {
        f32x4 wk = *(const f32x4*)(wb + (tu<<9) + ((k ^ swu)<<4));
        f32x4 s0 = s0p[k];
        f32x4 s1 = s1p[k];
        acc0 -= wk[0]*s0[0] + wk[1]*s0[1] + wk[2]*s0[2] + wk[3]*s0[3];
        acc1 -= wk[0]*s1[0] + wk[1]*s1[1] + wk[2]*s1[2] + wk[3]*s1[3];
      }
      us[tu][e0]   = acc0;
      us[tu][e0+1] = acc1;
      size_t ur = (size_t)(bh*128 + e_base + e0)*1024 + a + tu;
      Ut[ur]        = f2b(acc0);
      Ut[ur + 1024] = f2b(acc1);
    }
    __syncthreads();
    if (i < 15) {
      float ed = eD[ci];
      f32x4 sa = ed * *(f32x4*)&St[es][k4<<2];
      const char* kb = (const char*)&Kps[cur][0];
      #pragma unroll 8
      for (int t = 0; t < 64; ++t) {
        f32x4 kp = *(const f32x4*)(kb + (t<<9) + ((k4 ^ (t&7))<<4));
        float uv = us[t][es];
        sa += kp * uv;
      }
      *(f32x4*)&St[es][k4<<2] = sa;
      wv = wv_next;
    }
    __syncthreads();
  }
}

// -------- MFMA log-linear readout v3: LDS-staged K/Ut, double-buffered --------
__global__ __launch_bounds__(256) void readout3(const ushort* __restrict__ Qb,
    const ushort* __restrict__ Kb, const ushort* __restrict__ Ut,
    const float* __restrict__ gcg, const float* __restrict__ xs,
    float* __restrict__ Og)
{
  int blk = blockIdx.x;
  int bh = blk >> 4, ic = blk & 15;
  int half = blockIdx.y;
  int b = bh >> 3, h = bh & 7;
  int tbase = ic << 6;
  __shared__ ushort Ks[2][8192];       // 16 KB: 64 rows x 256B, col16 ^= row&15
  __shared__ ushort Us[2][8192];       // 16 KB: 128 rows x 128B, col16 ^= d&7
  __shared__ ushort Pl[4][1024];       // 16x64 bf16 per wave, XOR-swizzled
  __shared__ float lamS[64][12];
  int tid = threadIdx.x;
  int wave = tid >> 6, lane = tid & 63;
  int l15 = lane & 15, kh = lane >> 4;

  const char* kgb = (const char*)Kb + ((size_t)(b*1024)*1024 + h*128)*2;
  const char* ugb = (const char*)Ut + ((size_t)(bh*128)*1024)*2;

  for (int e = tid; e < 64*11; e += 256) {
    int t = e/11, l = e%11;
    lamS[t][l] = sigm(xs[(size_t)(b*1024+tbase+t)*104 + 16 + h*11 + l]);
  }
  int tl = kh*4;
  float gct_r[4];
  #pragma unroll
  for (int r = 0; r < 4; ++r) gct_r[r] = gcg[bh*1024 + tbase + wave*16 + tl + r];
  bf16x8 qf[4];
  {
    const ushort* qp = &Qb[(size_t)(b*1024 + tbase + wave*16 + l15)*1024 + h*128 + kh*8];
    #pragma unroll
    for (int kk = 0; kk < 4; ++kk) qf[kk] = *(const bf16x8*)(qp + kk*32);
  }

  f32x4 accO[8] = {};
  int nsteps = ic + 1;
  int jmid = (nsteps + 1) >> 1;
  int j0 = half ? jmid : 0;
  int j1 = half ? nsteps : jmid;
  ushort* Pw = &Pl[wave][0];

  if (j0 < j1) {
    {
      const char* kg = kgb + (size_t)(j0<<6)*2048;
      const char* ug = ugb + (size_t)(j0<<6)*2;
      #pragma unroll
      for (int it = 0; it < 4; ++it) {
        unsigned off = (it<<12) + (tid<<4);
        unsigned krow = off >> 8, kc = (off >> 4) & 15;
        unsigned ksrc = krow*2048 + ((kc ^ (krow & 15)) << 4);
        __builtin_amdgcn_global_load_lds((const __attribute__((address_space(1))) unsigned*)(kg + ksrc),
          (__attribute__((address_space(3))) unsigned*)((char*)&Ks[0][0] + off), 16, 0, 0);
        unsigned ud = off >> 7, uc = (off >> 4) & 7;
        unsigned usrc = ud*2048 + ((uc ^ (ud & 7)) << 4);
        __builtin_amdgcn_global_load_lds((const __attribute__((address_space(1))) unsigned*)(ug + usrc),
          (__attribute__((address_space(3))) unsigned*)((char*)&Us[0][0] + off), 16, 0, 0);
      }
    }
    __syncthreads();
    int cur = 0;
    for (int j = j0; j < j1; ++j) {
      int sbase = j << 6;
      if (j + 1 < j1) {
        const char* kg = kgb + (size_t)((j+1)<<6)*2048;
        const char* ug = ugb + (size_t)((j+1)<<6)*2;
        char* kl = (char*)&Ks[cur^1][0];
        char* ul = (char*)&Us[cur^1][0];
        #pragma unroll
        for (int it = 0; it < 4; ++it) {
          unsigned off = (it<<12) + (tid<<4);
          unsigned krow = off >> 8, kc = (off >> 4) & 15;
          unsigned ksrc = krow*2048 + ((kc ^ (krow & 15)) << 4);
          __builtin_amdgcn_global_load_lds((const __attribute__((address_space(1))) unsigned*)(kg + ksrc),
            (__attribute__((address_space(3))) unsigned*)(kl + off), 16, 0, 0);
          unsigned ud = off >> 7, uc = (off >> 4) & 7;
          unsigned usrc = ud*2048 + ((uc ^ (ud & 7)) << 4);
          __builtin_amdgcn_global_load_lds((const __attribute__((address_space(1))) unsigned*)(ug + usrc),
            (__attribute__((address_space(3))) unsigned*)(ul + off), 16, 0, 0);
        }
      }
      float gcs_r[4];
      #pragma unroll
      for (int jt = 0; jt < 4; ++jt)
        gcs_r[jt] = gcg[bh*1024 + sbase + jt*16 + l15];
      f32x4 accS[4] = {};
      const char* ksb = (const char*)&Ks[cur][0];
      #pragma unroll
      for (int jt = 0; jt < 4; ++jt) {
        int row = jt*16 + l15;
        int rsw = row & 15;
        #pragma unroll
        for (int kk = 0; kk < 4; ++kk) {
          bf16x8 kf = *(const bf16x8*)(ksb + row*256 + (((kk*4 + kh) ^ rsw) << 4));
          accS[jt] = __builtin_amdgcn_mfma_f32_16x16x32_bf16(qf[kk], kf, accS[jt], 0, 0, 0);
        }
      }
      #pragma unroll
      for (int jt = 0; jt < 4; ++jt) {
        int sg = sbase + jt*16 + l15;
        #pragma unroll
        for (int r = 0; r < 4; ++r) {
          int t_loc = tl + r;
          int tg = tbase + wave*16 + t_loc;
          float pv = 0.f;
          if (sg <= tg) {
            int lev = 31 - __clz((unsigned)((tg+1) ^ sg));
            lev = lev > 10 ? 10 : lev;
            pv = accS[jt][r] * __expf(gct_r[r] - gcs_r[jt]) * lamS[wave*16 + t_loc][lev];
          }
          int bo = (t_loc << 7) + ((jt*16 + l15) << 1);
          bo ^= (t_loc & 7) << 4;
          *(ushort*)((char*)Pw + bo) = f2b(pv);
        }
      }
      const char* usb = (const char*)&Us[cur][0];
      #pragma unroll
      for (int ks = 0; ks < 2; ++ks) {
        int bo = (l15 << 7) + ((ks*32 + kh*8) << 1);
        bo ^= (l15 & 7) << 4;
        bf16x8 pa = *(bf16x8*)((char*)Pw + bo);
        #pragma unroll
        for (int dt = 0; dt < 8; ++dt) {
          int d = dt*16 + l15;
          bf16x8 uf = *(const bf16x8*)(usb + d*128 + (((ks*4 + kh) ^ (d & 7)) << 4));
          accO[dt] = __builtin_amdgcn_mfma_f32_16x16x32_bf16(pa, uf, accO[dt], 0, 0, 0);
        }
      }
      __syncthreads();
      cur ^= 1;
    }
  }
  float* og = Og + (size_t)half*2097152;
  #pragma unroll
  for (int dt = 0; dt < 8; ++dt) {
    #pragma unroll
    for (int r = 0; r < 4; ++r) {
      int row = tbase + wave*16 + tl + r;
      og[(size_t)(b*1024 + row)*1024 + h*128 + dt*16 + l15] = accO[dt][r];
    }
  }
}

// -------- gated RMSNorm (sums two partial O buffers) -> bf16 --------
__global__ __launch_bounds__(64) void normgate(const float* __restrict__ O1,
    const float* __restrict__ O2, const float* __restrict__ G,
    const float* __restrict__ norm_w, ushort* __restrict__ Y)
{
  int row = blockIdx.x;
  int lane = threadIdx.x;
  size_t base = (size_t)(row >> 3)*1024 + (size_t)(row & 7)*128;
  float2 oa = *(const float2*)&O1[base + lane*2];
  float2 ob = *(const float2*)&O2[base + lane*2];
  float ox = oa.x + ob.x, oy = oa.y + ob.y;
  float ss = ox*ox + oy*oy;
  #pragma unroll
  for (int m = 1; m < 64; m <<= 1) ss += __shfl_xor(ss, m);
  float r = rsqrtf(ss * (1.f/128.f) + 1e-5f);
  float2 g = *(const float2*)&G[base + lane*2];
  ushort2 y;
  y.x = f2b(ox * r * norm_w[lane*2+0] * (g.x * sigm(g.x)));
  y.y = f2b(oy * r * norm_w[lane*2+1] * (g.y * sigm(g.y)));
  *(ushort2*)&Y[base + lane*2] = y;
}

extern "C" void kernel_launch(void* const* d_in, const int* in_sizes, int n_in,
                              void* d_out, int out_size, void* d_ws, size_t ws_size,
                              hipStream_t stream)
{
  const float* x    = (const float*)d_in[0];
  const float* Wq   = (const float*)d_in[3];
  const float* Wk   = (const float*)d_in[4];
  const float* Wv   = (const float*)d_in[5];
  const float* Wb   = (const float*)d_in[6];
  const float* Wa   = (const float*)d_in[7];
  const float* Wl   = (const float*)d_in[8];
  const float* Wg   = (const float*)d_in[9];
  const float* Wo   = (const float*)d_in[10];
  const float* cq   = (const float*)d_in[11];
  const float* ck   = (const float*)d_in[12];
  const float* cv   = (const float*)d_in[13];
  const float* A_log   = (const float*)d_in[14];
  const float* dt_bias = (const float*)d_in[15];
  const float* norm_w  = (const float*)d_in[16];
  float* out = (float*)d_out;

  float* p = (float*)d_ws;
  float* xqkv = p;  p += 6291456;            // [2048][3072] f32 (dead after convs)
  float* xg   = p;  p += 2097152;
  float* kb   = p;  p += 2097152;
  float* vb   = p;  p += 2097152;
  float* o1   = p;  p += 2097152;            // o1,o2 MUST be adjacent (readout3 half offset)
  float* o2   = p;  p += 2097152;
  float* xs   = p;  p += 212992;
  float* gc   = p;  p += 16384;
  float* eD   = p;  p += 256;
  // NOTE: p is float*; every 2M-ushort (4MB) bf16 buffer needs p += 1048576
  ushort* x16 = (ushort*)p; p += 1048576;    // [2048][1024] bf16
  ushort* Wt4 = (ushort*)p; p += 2097152;    // [4096][1024] bf16
  ushort* Wot = (ushort*)p; p += 524288;     // [1024][1024] bf16
  float* Wsm  = p;  p += 106496;
  ushort* yb16= (ushort*)p; p += 1048576;    // [2048][1024] bf16
  ushort* qb16= (ushort*)p; p += 1048576;    // [2048][1024] bf16
  ushort* kb16= (ushort*)p; p += 1048576;    // [2048][1024] bf16
  ushort* ut16= (ushort*)p; p += 1048576;    // [16*128][1024] bf16
  float* cw  = xqkv;                          // overlay dead xqkv
  float* cWk = xqkv + 2097152;
  float* cKp = xqkv + 4194304;
  float* part = o1;                           // [8][2048][104] partials; o1 dead until readout3

  dim3 blk(256);
  cast_x<<<dim3(2048), blk, 0, stream>>>(x, x16);
  transcast<<<dim3(32,32), blk, 0, stream>>>(Wq, Wt4);
  transcast<<<dim3(32,32), blk, 0, stream>>>(Wk, Wt4 + 1024*1024);
  transcast<<<dim3(32,32), blk, 0, stream>>>(Wv, Wt4 + 2*1024*1024);
  transcast<<<dim3(32,32), blk, 0, stream>>>(Wg, Wt4 + 3*1024*1024);
  transcast<<<dim3(32,32), blk, 0, stream>>>(Wo, Wot);
  copy_wsmall<<<dim3(416), blk, 0, stream>>>(Wb, Wa, Wl, Wsm);
  gemm_bf16<<<dim3(32,16), blk, 0, stream>>>(x16, Wt4, xqkv, xg, 2048, 4096, 1024,
                                             3072, 3072, 1024);
  skinny104<<<dim3(32,8), blk, 0, stream>>>(x, Wsm, part);
  reduce8<<<dim3(833), blk, 0, stream>>>(part, xs);
  conv_silu<<<dim3(2048), blk, 0, stream>>>(xqkv + 0,    cq, nullptr, qb16, 0, 3072);
  conv_silu<<<dim3(2048), blk, 0, stream>>>(xqkv + 1024, ck, kb, kb16, 1, 3072);
  conv_silu<<<dim3(2048), blk, 0, stream>>>(xqkv + 2048, cv, vb, nullptr, 2, 3072);
  gc2<<<dim3(16), blk, 0, stream>>>(xs, A_log, dt_bias, gc);
  chunk_prep<<<dim3(256), blk, 0, stream>>>(kb, vb, xs, gc, cw, cWk, cKp, eD);
  chunk_scan2<<<dim3(256), blk, 0, stream>>>(cw, cWk, cKp, eD, ut16);
  readout3<<<dim3(256,2), blk, 0, stream>>>(qb16, kb16, ut16, gc, xs, o1);
  normgate<<<dim3(16384), dim3(64), 0, stream>>>(o1, o2, xg, norm_w, yb16);
  gemm_bf16<<<dim3(8,16), blk, 0, stream>>>(yb16, Wot, out, out, 2048, 1024, 1024,
                                            1024, 1024, 1024);
}